// Round 2
// baseline (495.165 us; speedup 1.0000x reference)
//
#include <hip/hip_runtime.h>
#include <hip/hip_bf16.h>
#include <math.h>

#define B_   8
#define S_   4096
#define FIN  256
#define C_   256
#define G_   8
#define D_   32
#define K_   31
#define PAD_ 15
#define FOUT 88

// ---------------- Kernel 0: transpose rel [C,K] -> relT [K,C] --------------
__global__ void rel_transpose(const float* __restrict__ rel, float* __restrict__ relT) {
    int i = blockIdx.x * 256 + threadIdx.x;           // 31*256 = 7936
    if (i < K_ * C_) {
        int k = i >> 8, c = i & 255;
        relT[i] = rel[c * K_ + k];
    }
}

// ---------------- Kernel 1: fused QKV projection GEMM ----------------
__global__ __launch_bounds__(256) void qkv_gemm(
    const float* __restrict__ spec,
    const float* __restrict__ Wq, const float* __restrict__ Wk, const float* __restrict__ Wv,
    float* __restrict__ Q, float* __restrict__ Kb, float* __restrict__ Vb)
{
    __shared__ float As[16][64];
    __shared__ float Bs[16][64];

    const int nt = blockIdx.x;
    const int mt = blockIdx.y;
    const int w  = nt >> 2;
    const float* __restrict__ W   = (w == 0) ? Wq : (w == 1) ? Wk : Wv;
    float* __restrict__ Out       = (w == 0) ? Q  : (w == 1) ? Kb : Vb;
    const int n0 = (nt & 3) * 64;
    const int m0 = mt * 64;

    const int t  = threadIdx.x;
    const int tx = t & 15;
    const int ty = t >> 4;
    const int lr  = t >> 2;
    const int lk  = (t & 3) * 4;
    const int lbr = t >> 4;
    const int lbc = (t & 15) * 4;

    float acc[4][4] = {};

    for (int k0 = 0; k0 < 256; k0 += 16) {
        float4 a = *(const float4*)&spec[(size_t)(m0 + lr) * 256 + k0 + lk];
        As[lk + 0][lr] = a.x;
        As[lk + 1][lr] = a.y;
        As[lk + 2][lr] = a.z;
        As[lk + 3][lr] = a.w;
        *(float4*)&Bs[lbr][lbc] = *(const float4*)&W[(size_t)(k0 + lbr) * 256 + n0 + lbc];
        __syncthreads();
#pragma unroll
        for (int kk = 0; kk < 16; ++kk) {
            float4 a4 = *(const float4*)&As[kk][ty * 4];
            float4 b4 = *(const float4*)&Bs[kk][tx * 4];
            acc[0][0] += a4.x * b4.x; acc[0][1] += a4.x * b4.y; acc[0][2] += a4.x * b4.z; acc[0][3] += a4.x * b4.w;
            acc[1][0] += a4.y * b4.x; acc[1][1] += a4.y * b4.y; acc[1][2] += a4.y * b4.z; acc[1][3] += a4.y * b4.w;
            acc[2][0] += a4.z * b4.x; acc[2][1] += a4.z * b4.y; acc[2][2] += a4.z * b4.z; acc[2][3] += a4.z * b4.w;
            acc[3][0] += a4.w * b4.x; acc[3][1] += a4.w * b4.y; acc[3][2] += a4.w * b4.z; acc[3][3] += a4.w * b4.w;
        }
        __syncthreads();
    }
#pragma unroll
    for (int i = 0; i < 4; ++i) {
        float4 o = make_float4(acc[i][0], acc[i][1], acc[i][2], acc[i][3]);
        *(float4*)&Out[(size_t)(m0 + ty * 4 + i) * 256 + n0 + tx * 4] = o;
    }
}

// ---------------- Kernel 2: wave-per-row windowed attention ----------------
// One 64-lane wave owns one s-row (all 8 heads). lane l covers cols 4l..4l+3,
// head g = l>>3. All K/V/rel loads are 1 coalesced dwordx4 per wave per row.
// O overwrites Q in place (each wave reads only its own Q row).
__global__ __launch_bounds__(256) void attn_wave(
    float* __restrict__ Q,                 // in: Q rows; out: O rows (aliased)
    const float* __restrict__ Kb, const float* __restrict__ Vb,
    const float* __restrict__ relT,        // [K][C]
    float* __restrict__ attn)
{
    const int w    = (blockIdx.x * 256 + threadIdx.x) >> 6;   // global row 0..32767
    const int lane = threadIdx.x & 63;
    const int b    = w >> 12;
    const int s    = w & 4095;
    const size_t rowoff = (size_t)w * 256 + lane * 4;
    const size_t kvbase = ((size_t)b * S_) * 256 + lane * 4;

    const float4 q4 = *(const float4*)&Q[rowoff];

    // ---- energy + 8-lane group reduce ----
    float e[31];
#pragma unroll
    for (int k = 0; k < K_; ++k) {
        const int s2 = s - PAD_ + k;
        const float4 rv = *(const float4*)&relT[(k << 8) + lane * 4];
        float p;
        if ((unsigned)s2 < (unsigned)S_) {
            const float4 kv = *(const float4*)&Kb[kvbase + (size_t)s2 * 256];
            p = q4.x * (kv.x + rv.x) + q4.y * (kv.y + rv.y)
              + q4.z * (kv.z + rv.z) + q4.w * (kv.w + rv.w);
        } else {
            p = q4.x * rv.x + q4.y * rv.y + q4.z * rv.z + q4.w * rv.w;
        }
        p += __shfl_xor(p, 1, 64);
        p += __shfl_xor(p, 2, 64);
        p += __shfl_xor(p, 4, 64);
        e[k] = p;                     // all 8 lanes of group g hold e_g[k]
    }

    // ---- softmax over K=31 in registers ----
    float mx = e[0];
#pragma unroll
    for (int k = 1; k < K_; ++k) mx = fmaxf(mx, e[k]);
    float sum = 0.f;
#pragma unroll
    for (int k = 0; k < K_; ++k) { e[k] = __expf(e[k] - mx); sum += e[k]; }
    const float inv = 1.f / sum;
#pragma unroll
    for (int k = 0; k < K_; ++k) e[k] *= inv;

    // ---- attn store: lane (l&7)==(k&7) of each group writes e[k] ----
    {
        const int g = lane >> 3;
        float* ap = &attn[(size_t)w * (G_ * K_) + g * K_];
        const int kq = lane & 7;
#pragma unroll
        for (int k = 0; k < K_; ++k) {
            if (kq == (k & 7)) ap[k] = e[k];
        }
    }

    // ---- PV ----
    float4 o4 = make_float4(0.f, 0.f, 0.f, 0.f);
#pragma unroll
    for (int k = 0; k < K_; ++k) {
        const int s2 = s - PAD_ + k;
        if ((unsigned)s2 < (unsigned)S_) {
            const float4 v4 = *(const float4*)&Vb[kvbase + (size_t)s2 * 256];
            const float a = e[k];
            o4.x += a * v4.x; o4.y += a * v4.y; o4.z += a * v4.z; o4.w += a * v4.w;
        }
    }
    *(float4*)&Q[rowoff] = o4;        // O aliases Q
}

// ---------------- Kernel 3: frame = sigmoid(O @ Wl + b) --------------------
// M-tile 64 rows, N=88 full, K-chunks of 64. Wl chunk in LDS (broadcast reads),
// O chunk in LDS. Thread: 2 rows x 11 cols (f = tx + 8j).
__global__ __launch_bounds__(256) void frame_gemm(
    const float* __restrict__ O, const float* __restrict__ Wl,
    const float* __restrict__ bl, float* __restrict__ frame)
{
    __shared__ float O_s[64 * 65];      // pitch 65
    __shared__ float Wl_s[64 * 89];     // pitch 89

    const int r0 = blockIdx.x * 64;
    const int t  = threadIdx.x;
    const int tm = t >> 3;              // 0..31 -> rows 2tm, 2tm+1
    const int tx = t & 7;               // f = tx + 8j

    // stage indices
    const int lr = t >> 2;              // 0..63
    const int lc = (t & 3) * 16;        // 0,16,32,48

    float acc[2][11] = {};

    for (int c0 = 0; c0 < 256; c0 += 64) {
        __syncthreads();
        // O chunk: 64 rows x 64 cols
#pragma unroll
        for (int i = 0; i < 4; ++i) {
            float4 v = *(const float4*)&O[(size_t)(r0 + lr) * 256 + c0 + lc + 4 * i];
            *(float4*)&O_s[lr * 65 + lc + 4 * i] = v;
        }
        // Wl chunk: 64 x 88
        for (int i = t; i < 64 * 88; i += 256) {
            int c = i / 88;
            int f = i - c * 88;
            Wl_s[c * 89 + f] = Wl[(size_t)c0 * 88 + i];
        }
        __syncthreads();
#pragma unroll
        for (int c = 0; c < 64; ++c) {
            float ov0 = O_s[(2 * tm) * 65 + c];
            float ov1 = O_s[(2 * tm + 1) * 65 + c];
#pragma unroll
            for (int j = 0; j < 11; ++j) {
                float wv = Wl_s[c * 89 + tx + 8 * j];
                acc[0][j] += ov0 * wv;
                acc[1][j] += ov1 * wv;
            }
        }
    }

#pragma unroll
    for (int i = 0; i < 2; ++i) {
        const size_t row = (size_t)(r0 + 2 * tm + i);
#pragma unroll
        for (int j = 0; j < 11; ++j) {
            const int f = tx + 8 * j;
            float x = acc[i][j] + bl[f];
            frame[row * FOUT + f] = 1.f / (1.f + __expf(-x));
        }
    }
}

extern "C" void kernel_launch(void* const* d_in, const int* in_sizes, int n_in,
                              void* d_out, int out_size, void* d_ws, size_t ws_size,
                              hipStream_t stream) {
    (void)in_sizes; (void)n_in; (void)out_size; (void)ws_size;
    const float* spec = (const float*)d_in[0];
    const float* Wq   = (const float*)d_in[1];
    const float* Wk   = (const float*)d_in[2];
    const float* Wv   = (const float*)d_in[3];
    const float* rel  = (const float*)d_in[4];
    const float* Wl   = (const float*)d_in[5];
    const float* bl   = (const float*)d_in[6];

    float* frame = (float*)d_out;                              // [B,S,88]
    float* attn  = frame + (size_t)B_ * S_ * FOUT;             // [B,S,G,K]

    float* Q    = (float*)d_ws;                                // [B*S,256] (becomes O)
    float* Kb   = Q  + (size_t)B_ * S_ * C_;
    float* Vb   = Kb + (size_t)B_ * S_ * C_;
    float* relT = Vb + (size_t)B_ * S_ * C_;                   // [31,256]

    rel_transpose<<<dim3(31), 256, 0, stream>>>(rel, relT);
    qkv_gemm<<<dim3(12, 512), 256, 0, stream>>>(spec, Wq, Wk, Wv, Q, Kb, Vb);
    attn_wave<<<dim3((B_ * S_ * 64) / 256), 256, 0, stream>>>(Q, Kb, Vb, relT, attn);
    frame_gemm<<<dim3(B_ * S_ / 64), 256, 0, stream>>>(Q, Wl, bl, frame);
}

// Round 3
// 371.305 us; speedup vs baseline: 1.3336x; 1.3336x over previous
//
#include <hip/hip_runtime.h>
#include <hip/hip_bf16.h>
#include <math.h>

#define B_   8
#define S_   4096
#define FIN  256
#define C_   256
#define G_   8
#define D_   32
#define K_   31
#define PAD_ 15
#define FOUT 88

// ---------------- Kernel 0: transpose rel [C,K] -> relT [K,C] --------------
__global__ void rel_transpose(const float* __restrict__ rel, float* __restrict__ relT) {
    int i = blockIdx.x * 256 + threadIdx.x;           // 31*256 = 7936
    if (i < K_ * C_) {
        int k = i >> 8, c = i & 255;
        relT[i] = rel[c * K_ + k];
    }
}

// ---------------- Kernel 1: fused QKV projection GEMM ----------------
__global__ __launch_bounds__(256) void qkv_gemm(
    const float* __restrict__ spec,
    const float* __restrict__ Wq, const float* __restrict__ Wk, const float* __restrict__ Wv,
    float* __restrict__ Q, float* __restrict__ Kb, float* __restrict__ Vb)
{
    __shared__ float As[16][64];
    __shared__ float Bs[16][64];

    const int nt = blockIdx.x;
    const int mt = blockIdx.y;
    const int w  = nt >> 2;
    const float* __restrict__ W   = (w == 0) ? Wq : (w == 1) ? Wk : Wv;
    float* __restrict__ Out       = (w == 0) ? Q  : (w == 1) ? Kb : Vb;
    const int n0 = (nt & 3) * 64;
    const int m0 = mt * 64;

    const int t  = threadIdx.x;
    const int tx = t & 15;
    const int ty = t >> 4;
    const int lr  = t >> 2;
    const int lk  = (t & 3) * 4;
    const int lbr = t >> 4;
    const int lbc = (t & 15) * 4;

    float acc[4][4] = {};

    for (int k0 = 0; k0 < 256; k0 += 16) {
        float4 a = *(const float4*)&spec[(size_t)(m0 + lr) * 256 + k0 + lk];
        As[lk + 0][lr] = a.x;
        As[lk + 1][lr] = a.y;
        As[lk + 2][lr] = a.z;
        As[lk + 3][lr] = a.w;
        *(float4*)&Bs[lbr][lbc] = *(const float4*)&W[(size_t)(k0 + lbr) * 256 + n0 + lbc];
        __syncthreads();
#pragma unroll
        for (int kk = 0; kk < 16; ++kk) {
            float4 a4 = *(const float4*)&As[kk][ty * 4];
            float4 b4 = *(const float4*)&Bs[kk][tx * 4];
            acc[0][0] += a4.x * b4.x; acc[0][1] += a4.x * b4.y; acc[0][2] += a4.x * b4.z; acc[0][3] += a4.x * b4.w;
            acc[1][0] += a4.y * b4.x; acc[1][1] += a4.y * b4.y; acc[1][2] += a4.y * b4.z; acc[1][3] += a4.y * b4.w;
            acc[2][0] += a4.z * b4.x; acc[2][1] += a4.z * b4.y; acc[2][2] += a4.z * b4.z; acc[2][3] += a4.z * b4.w;
            acc[3][0] += a4.w * b4.x; acc[3][1] += a4.w * b4.y; acc[3][2] += a4.w * b4.z; acc[3][3] += a4.w * b4.w;
        }
        __syncthreads();
    }
#pragma unroll
    for (int i = 0; i < 4; ++i) {
        float4 o = make_float4(acc[i][0], acc[i][1], acc[i][2], acc[i][3]);
        *(float4*)&Out[(size_t)(m0 + ty * 4 + i) * 256 + n0 + tx * 4] = o;
    }
}

// ---------------- Kernel 2: wave-per-2-rows windowed attention -------------
// One 64-lane wave owns rows (wrow, wrow+1), all 8 heads; lane l = cols 4l..4l+3.
// XCD-chunked swizzle: each XCD gets one contiguous batch (4096 rows) so the
// 31-row window reuse is XCD-L2-local. K loads batched 8-deep; per-lane
// partials for all 62 (row,k) pairs first, then 3 staged shuffle rounds.
__global__ __launch_bounds__(256) void attn_wave2(
    float* __restrict__ Q,                 // in: Q rows; out: O rows (aliased)
    const float* __restrict__ Kb, const float* __restrict__ Vb,
    const float* __restrict__ relT,        // [K][C]
    float* __restrict__ attn)
{
    const int bid  = blockIdx.x;                       // 0..4095
    const int bid2 = ((bid & 7) << 9) | (bid >> 3);    // XCD-chunked remap
    const int wid  = threadIdx.x >> 6;                 // wave in block 0..3
    const int lane = threadIdx.x & 63;
    const int wrow = bid2 * 8 + wid * 2;               // rows wrow, wrow+1
    const int b    = wrow >> 12;
    const int s    = wrow & 4095;                      // s, s+1 (same batch)
    const int col  = lane * 4;
    const size_t kvbase = (size_t)(b << 12) * 256 + col;

    const float4 q0 = *(const float4*)&Q[(size_t)wrow * 256 + col];
    const float4 q1 = *(const float4*)&Q[(size_t)(wrow + 1) * 256 + col];

    float p0[31], p1[31];
    float4 rvp = make_float4(0.f, 0.f, 0.f, 0.f);      // rel[kk-1]

    // ---- energy partials (per-lane 4-dim dots), K rows batched 8-deep ----
#pragma unroll
    for (int kb = 0; kb < 4; ++kb) {
        float4 kbuf[8];
#pragma unroll
        for (int j = 0; j < 8; ++j) {
            const int s2 = s - PAD_ + kb * 8 + j;
            kbuf[j] = ((unsigned)s2 < (unsigned)S_)
                    ? *(const float4*)&Kb[kvbase + (size_t)s2 * 256]
                    : make_float4(0.f, 0.f, 0.f, 0.f);
        }
#pragma unroll
        for (int j = 0; j < 8; ++j) {
            const int kk = kb * 8 + j;
            const float4 kv = kbuf[j];
            float4 rv = make_float4(0.f, 0.f, 0.f, 0.f);
            if (kk < K_) rv = *(const float4*)&relT[(kk << 8) + col];
            if (kk < K_)
                p0[kk] = q0.x*(kv.x+rv.x) + q0.y*(kv.y+rv.y)
                       + q0.z*(kv.z+rv.z) + q0.w*(kv.w+rv.w);
            if (kk >= 1)
                p1[kk-1] = q1.x*(kv.x+rvp.x) + q1.y*(kv.y+rvp.y)
                         + q1.z*(kv.z+rvp.z) + q1.w*(kv.w+rvp.w);
            rvp = rv;
        }
    }

    // ---- staged 8-lane-group reduction (62 independent chains/stage) ----
#pragma unroll
    for (int k = 0; k < K_; ++k) { p0[k] += __shfl_xor(p0[k], 1, 64); p1[k] += __shfl_xor(p1[k], 1, 64); }
#pragma unroll
    for (int k = 0; k < K_; ++k) { p0[k] += __shfl_xor(p0[k], 2, 64); p1[k] += __shfl_xor(p1[k], 2, 64); }
#pragma unroll
    for (int k = 0; k < K_; ++k) { p0[k] += __shfl_xor(p0[k], 4, 64); p1[k] += __shfl_xor(p1[k], 4, 64); }

    // ---- softmax (both rows, replicated across the 8-lane group) ----
    float mx0 = p0[0], mx1 = p1[0];
#pragma unroll
    for (int k = 1; k < K_; ++k) { mx0 = fmaxf(mx0, p0[k]); mx1 = fmaxf(mx1, p1[k]); }
    float sm0 = 0.f, sm1 = 0.f;
#pragma unroll
    for (int k = 0; k < K_; ++k) {
        p0[k] = __expf(p0[k] - mx0); sm0 += p0[k];
        p1[k] = __expf(p1[k] - mx1); sm1 += p1[k];
    }
    const float in0 = 1.f / sm0, in1 = 1.f / sm1;
#pragma unroll
    for (int k = 0; k < K_; ++k) { p0[k] *= in0; p1[k] *= in1; }

    // ---- attn stores: lane (l&7)==(k&7) of each head group writes ----
    {
        const int g  = lane >> 3;
        const int kq = lane & 7;
        float* a0 = &attn[(size_t)wrow * (G_ * K_) + g * K_];
        float* a1 = a0 + G_ * K_;
#pragma unroll
        for (int k = 0; k < K_; ++k) {
            if (kq == (k & 7)) { a0[k] = p0[k]; a1[k] = p1[k]; }
        }
    }

    // ---- PV, V rows batched 8-deep ----
    float4 o0 = make_float4(0.f, 0.f, 0.f, 0.f);
    float4 o1 = make_float4(0.f, 0.f, 0.f, 0.f);
#pragma unroll
    for (int kb = 0; kb < 4; ++kb) {
        float4 vbuf[8];
#pragma unroll
        for (int j = 0; j < 8; ++j) {
            const int s2 = s - PAD_ + kb * 8 + j;
            vbuf[j] = ((unsigned)s2 < (unsigned)S_)
                    ? *(const float4*)&Vb[kvbase + (size_t)s2 * 256]
                    : make_float4(0.f, 0.f, 0.f, 0.f);
        }
#pragma unroll
        for (int j = 0; j < 8; ++j) {
            const int kk = kb * 8 + j;
            const float4 vv = vbuf[j];
            if (kk < K_) {
                const float a = p0[kk];
                o0.x += a * vv.x; o0.y += a * vv.y; o0.z += a * vv.z; o0.w += a * vv.w;
            }
            if (kk >= 1) {
                const float a = p1[kk-1];
                o1.x += a * vv.x; o1.y += a * vv.y; o1.z += a * vv.z; o1.w += a * vv.w;
            }
        }
    }
    *(float4*)&Q[(size_t)wrow * 256 + col]       = o0;   // O aliases Q
    *(float4*)&Q[(size_t)(wrow + 1) * 256 + col] = o1;
}

// ---------------- Kernel 3: frame = sigmoid(O @ Wl + b) --------------------
// 128-row blocks, 4 rows/thread: 15 LDS reads per 44 FMA.
__global__ __launch_bounds__(256) void frame_gemm(
    const float* __restrict__ O, const float* __restrict__ Wl,
    const float* __restrict__ bl, float* __restrict__ frame)
{
    __shared__ float O_s[128 * 65];     // 33.3 KB
    __shared__ float Wl_s[64 * 89];     // 22.8 KB

    const int r0 = blockIdx.x * 128;
    const int t  = threadIdx.x;
    const int tm = t >> 3;              // 0..31 -> rows 4tm..4tm+3
    const int tx = t & 7;               // f = tx + 8j

    const int lr = t >> 1;              // 0..127
    const int lc = (t & 1) * 32;

    float acc[4][11] = {};

    for (int c0 = 0; c0 < 256; c0 += 64) {
        __syncthreads();
#pragma unroll
        for (int i = 0; i < 8; ++i) {
            float4 v = *(const float4*)&O[(size_t)(r0 + lr) * 256 + c0 + lc + 4 * i];
            *(float4*)&O_s[lr * 65 + lc + 4 * i] = v;
        }
        for (int i = t; i < 64 * 88; i += 256) {
            int c = i / 88;
            int f = i - c * 88;
            Wl_s[c * 89 + f] = Wl[(size_t)c0 * 88 + i];
        }
        __syncthreads();
#pragma unroll
        for (int c = 0; c < 64; ++c) {
            float ov0 = O_s[(4 * tm + 0) * 65 + c];
            float ov1 = O_s[(4 * tm + 1) * 65 + c];
            float ov2 = O_s[(4 * tm + 2) * 65 + c];
            float ov3 = O_s[(4 * tm + 3) * 65 + c];
#pragma unroll
            for (int j = 0; j < 11; ++j) {
                float wv = Wl_s[c * 89 + tx + 8 * j];
                acc[0][j] += ov0 * wv;
                acc[1][j] += ov1 * wv;
                acc[2][j] += ov2 * wv;
                acc[3][j] += ov3 * wv;
            }
        }
    }

#pragma unroll
    for (int i = 0; i < 4; ++i) {
        const size_t row = (size_t)(r0 + 4 * tm + i);
#pragma unroll
        for (int j = 0; j < 11; ++j) {
            const int f = tx + 8 * j;
            float x = acc[i][j] + bl[f];
            frame[row * FOUT + f] = 1.f / (1.f + __expf(-x));
        }
    }
}

extern "C" void kernel_launch(void* const* d_in, const int* in_sizes, int n_in,
                              void* d_out, int out_size, void* d_ws, size_t ws_size,
                              hipStream_t stream) {
    (void)in_sizes; (void)n_in; (void)out_size; (void)ws_size;
    const float* spec = (const float*)d_in[0];
    const float* Wq   = (const float*)d_in[1];
    const float* Wk   = (const float*)d_in[2];
    const float* Wv   = (const float*)d_in[3];
    const float* rel  = (const float*)d_in[4];
    const float* Wl   = (const float*)d_in[5];
    const float* bl   = (const float*)d_in[6];

    float* frame = (float*)d_out;                              // [B,S,88]
    float* attn  = frame + (size_t)B_ * S_ * FOUT;             // [B,S,G,K]

    float* Q    = (float*)d_ws;                                // [B*S,256] (becomes O)
    float* Kb   = Q  + (size_t)B_ * S_ * C_;
    float* Vb   = Kb + (size_t)B_ * S_ * C_;
    float* relT = Vb + (size_t)B_ * S_ * C_;                   // [31,256]

    rel_transpose<<<dim3(31), 256, 0, stream>>>(rel, relT);
    qkv_gemm<<<dim3(12, 512), 256, 0, stream>>>(spec, Wq, Wk, Wv, Q, Kb, Vb);
    attn_wave2<<<dim3(4096), 256, 0, stream>>>(Q, Kb, Vb, relT, attn);
    frame_gemm<<<dim3(B_ * S_ / 128), 256, 0, stream>>>(Q, Wl, bl, frame);
}

// Round 4
// 275.502 us; speedup vs baseline: 1.7973x; 1.3477x over previous
//
#include <hip/hip_runtime.h>
#include <hip/hip_bf16.h>
#include <math.h>

#define B_   8
#define S_   4096
#define FIN  256
#define C_   256
#define G_   8
#define D_   32
#define K_   31
#define PAD_ 15
#define FOUT 88

typedef __bf16 bf16;
typedef __attribute__((ext_vector_type(8))) __bf16 bf16x8;
typedef __attribute__((ext_vector_type(4))) float f32x4;

// ---------------- Kernel A: split spec fp32 -> bf16 hi/lo ----------------
__global__ __launch_bounds__(256) void split_spec(
    const float* __restrict__ spec, bf16* __restrict__ sh, bf16* __restrict__ sl)
{
    const size_t base = ((size_t)blockIdx.x * 256 + threadIdx.x) * 8;   // 8.39M elems total
    float4 x0 = *(const float4*)&spec[base];
    float4 x1 = *(const float4*)&spec[base + 4];
    float xs[8] = {x0.x, x0.y, x0.z, x0.w, x1.x, x1.y, x1.z, x1.w};
    bf16x8 H, L;
#pragma unroll
    for (int j = 0; j < 8; ++j) {
        bf16 h = (bf16)xs[j];
        H[j] = h;
        L[j] = (bf16)(xs[j] - (float)h);
    }
    *(bf16x8*)&sh[base] = H;
    *(bf16x8*)&sl[base] = L;
}

// ---------------- Kernel B: split + transpose weights -> Bt[w][n][k] -------
__global__ void split_w(const float* __restrict__ Wq, const float* __restrict__ Wk,
                        const float* __restrict__ Wv,
                        bf16* __restrict__ bth, bf16* __restrict__ btl)
{
    const int k = blockIdx.x;          // 0..255
    const int w = blockIdx.y;          // 0..2
    const int n = threadIdx.x;         // 0..255
    const float* W = (w == 0) ? Wq : (w == 1) ? Wk : Wv;
    float x = W[(size_t)k * 256 + n];
    bf16 h = (bf16)x;
    bf16 l = (bf16)(x - (float)h);
    size_t o = (size_t)w * 65536 + (size_t)n * 256 + k;
    bth[o] = h;
    btl[o] = l;
}

// ---------------- Kernel C: transpose rel [C,K] -> relT [K,C] --------------
__global__ void rel_transpose(const float* __restrict__ rel, float* __restrict__ relT) {
    int i = blockIdx.x * 256 + threadIdx.x;           // 31*256 = 7936
    if (i < K_ * C_) {
        int k = i >> 8, c = i & 255;
        relT[i] = rel[c * K_ + k];
    }
}

// ---------------- Kernel 1: QKV projection, MFMA split-bf16 ----------------
// C[32768, 768] = A[32768,256] @ [Wq|Wk|Wv]. Q,K: 3-term split; V: 2-term.
// 128x128 tile, BK=32, 4 waves (each 64x64 = 4x4 frags of 16x16x32 bf16).
// LDS: Ah|Al|Bh|Bl, each [128 rows][32 k] bf16, 16B-chunk XOR swizzle
// (chunk ^= (row>>1)&3) applied on global_load_lds SOURCE and ds_read.
__device__ __forceinline__ void gload16(const bf16* g, bf16* l) {
    __builtin_amdgcn_global_load_lds(
        (const __attribute__((address_space(1))) void*)g,
        (__attribute__((address_space(3))) void*)l, 16, 0, 0);
}

__device__ __forceinline__ void stage_tile(const bf16* g, bf16* l, int t) {
    // chunk c = i*256 + t; row = c>>2; stored chunk = c&3; logical = stored ^ ((row>>1)&3)
    const int lg = ((t & 3) ^ ((t >> 3) & 3)) * 8;       // same for both instrs
    const int r0 = t >> 2;
    const int r1 = 64 + (t >> 2);
    const int u0 = (t & ~63) * 8;
    gload16(g + (size_t)r0 * 256 + lg, l + u0);
    gload16(g + (size_t)r1 * 256 + lg, l + u0 + 2048);
}

__device__ __forceinline__ bf16x8 frag_ld(const bf16* l, int r, int cl) {
    return *(const bf16x8*)&l[r * 32 + ((cl ^ ((r >> 1) & 3)) << 3)];
}

__global__ __launch_bounds__(256) void qkv_mfma(
    const bf16* __restrict__ sh, const bf16* __restrict__ sl,
    const bf16* __restrict__ bth, const bf16* __restrict__ btl,
    float* __restrict__ Q, float* __restrict__ Kb, float* __restrict__ Vb)
{
    __shared__ bf16 lds[4 * 4096];     // Ah | Al | Bh | Bl (8KB each)

    const int t   = threadIdx.x;
    const int swz = ((blockIdx.x & 7) * 192) + (blockIdx.x >> 3);   // 1536 % 8 == 0
    const int mt  = swz / 6, nt = swz % 6;
    const int wt  = nt >> 1;
    const int m0  = mt * 128, n0 = (nt & 1) * 128;
    const bool three = (wt < 2);       // Q,K: 3-term; V: 2-term
    float* __restrict__ Out = (wt == 0) ? Q : (wt == 1) ? Kb : Vb;

    const bf16* ah_g = sh  + (size_t)m0 * 256;
    const bf16* al_g = sl  + (size_t)m0 * 256;
    const bf16* bh_g = bth + (size_t)wt * 65536 + (size_t)n0 * 256;
    const bf16* bl_g = btl + (size_t)wt * 65536 + (size_t)n0 * 256;

    const int lane = t & 63, wid = t >> 6;
    const int wr = (wid >> 1) * 64, wc = (wid & 1) * 64;
    const int fr = lane & 15, cl = lane >> 4;

    f32x4 acc[4][4];
#pragma unroll
    for (int m = 0; m < 4; ++m)
#pragma unroll
        for (int n = 0; n < 4; ++n)
            acc[m][n] = (f32x4){0.f, 0.f, 0.f, 0.f};

    for (int ks = 0; ks < 8; ++ks) {
        const int ko = ks * 32;
        stage_tile(ah_g + ko, lds, t);
        if (three) stage_tile(al_g + ko, lds + 4096, t);
        stage_tile(bh_g + ko, lds + 8192, t);
        stage_tile(bl_g + ko, lds + 12288, t);
        __syncthreads();

        bf16x8 ah[4], bh[4], bl[4];
#pragma unroll
        for (int m = 0; m < 4; ++m) ah[m] = frag_ld(lds, wr + m * 16 + fr, cl);
#pragma unroll
        for (int n = 0; n < 4; ++n) {
            bh[n] = frag_ld(lds + 8192,  wc + n * 16 + fr, cl);
            bl[n] = frag_ld(lds + 12288, wc + n * 16 + fr, cl);
        }
#pragma unroll
        for (int m = 0; m < 4; ++m)
#pragma unroll
            for (int n = 0; n < 4; ++n) {
                acc[m][n] = __builtin_amdgcn_mfma_f32_16x16x32_bf16(ah[m], bh[n], acc[m][n], 0, 0, 0);
                acc[m][n] = __builtin_amdgcn_mfma_f32_16x16x32_bf16(ah[m], bl[n], acc[m][n], 0, 0, 0);
            }
        if (three) {
            bf16x8 al[4];
#pragma unroll
            for (int m = 0; m < 4; ++m) al[m] = frag_ld(lds + 4096, wr + m * 16 + fr, cl);
#pragma unroll
            for (int m = 0; m < 4; ++m)
#pragma unroll
                for (int n = 0; n < 4; ++n)
                    acc[m][n] = __builtin_amdgcn_mfma_f32_16x16x32_bf16(al[m], bh[n], acc[m][n], 0, 0, 0);
        }
        __syncthreads();
    }

    // C/D layout: col = lane&15, row = (lane>>4)*4 + reg  [m89/m91 verified]
#pragma unroll
    for (int m = 0; m < 4; ++m) {
        const int gr = m0 + wr + m * 16 + cl * 4;
#pragma unroll
        for (int n = 0; n < 4; ++n) {
            const int gc = n0 + wc + n * 16 + fr;
#pragma unroll
            for (int i = 0; i < 4; ++i)
                Out[(size_t)(gr + i) * 256 + gc] = acc[m][n][i];
        }
    }
}

// ---------------- Kernel 2: wave-per-2-rows windowed attention -------------
// rel staged in LDS; K loads 4-deep double-buffered; V batch 0/1 issued
// before the shuffle+softmax phase to hide latency under VALU work.
__global__ __launch_bounds__(256) void attn_wave3(
    float* __restrict__ Q,                 // in: Q rows; out: O rows (aliased)
    const float* __restrict__ Kb, const float* __restrict__ Vb,
    const float* __restrict__ relT,        // [K][C] in d_out scratch
    float* __restrict__ attn)
{
    __shared__ float rels[K_ * 256];       // 31.7 KB

    const int bid  = blockIdx.x;                       // 0..4095
    const int bid2 = ((bid & 7) << 9) | (bid >> 3);    // XCD-chunked remap
    const int wid  = threadIdx.x >> 6;
    const int lane = threadIdx.x & 63;
    const int wrow = bid2 * 8 + wid * 2;               // rows wrow, wrow+1
    const int b    = wrow >> 12;
    const int s    = wrow & 4095;
    const int col  = lane * 4;
    const size_t kvbase = (size_t)(b << 12) * 256 + col;

    for (int i = threadIdx.x; i < K_ * 256; i += 256) rels[i] = relT[i];
    __syncthreads();

    const float4 q0 = *(const float4*)&Q[(size_t)wrow * 256 + col];
    const float4 q1 = *(const float4*)&Q[(size_t)(wrow + 1) * 256 + col];

    float p0[31], p1[31];
    float4 bufA[4], bufB[4];
    float4 rvp = make_float4(0.f, 0.f, 0.f, 0.f);
    float4 o0  = make_float4(0.f, 0.f, 0.f, 0.f);
    float4 o1  = make_float4(0.f, 0.f, 0.f, 0.f);

#define LD4(BUF, SRC, BASE) { _Pragma("unroll") for (int j = 0; j < 4; ++j) { \
    const int s2 = s - PAD_ + (BASE) + j; \
    BUF[j] = ((unsigned)s2 < (unsigned)S_) ? *(const float4*)&SRC[kvbase + (size_t)s2 * 256] \
                                           : make_float4(0.f, 0.f, 0.f, 0.f); } }

#define DOT4(BUF, BASE) { _Pragma("unroll") for (int j = 0; j < 4; ++j) { \
    const int kk = (BASE) + j; \
    const float4 kv = BUF[j]; \
    float4 rv = make_float4(0.f, 0.f, 0.f, 0.f); \
    if (kk < K_) { rv = *(const float4*)&rels[(kk << 8) + col]; \
      p0[kk] = q0.x*(kv.x+rv.x) + q0.y*(kv.y+rv.y) + q0.z*(kv.z+rv.z) + q0.w*(kv.w+rv.w); } \
    if (kk >= 1) \
      p1[kk-1] = q1.x*(kv.x+rvp.x) + q1.y*(kv.y+rvp.y) + q1.z*(kv.z+rvp.z) + q1.w*(kv.w+rvp.w); \
    rvp = rv; } }

#define PV4(BUF, BASE) { _Pragma("unroll") for (int j = 0; j < 4; ++j) { \
    const int kk = (BASE) + j; \
    const float4 vv = BUF[j]; \
    if (kk < K_) { o0.x += p0[kk]*vv.x; o0.y += p0[kk]*vv.y; o0.z += p0[kk]*vv.z; o0.w += p0[kk]*vv.w; } \
    if (kk >= 1) { o1.x += p1[kk-1]*vv.x; o1.y += p1[kk-1]*vv.y; o1.z += p1[kk-1]*vv.z; o1.w += p1[kk-1]*vv.w; } } }

    // ---- energy partials, pipelined ----
    LD4(bufA, Kb, 0);  LD4(bufB, Kb, 4);
    DOT4(bufA, 0);     LD4(bufA, Kb, 8);
    DOT4(bufB, 4);     LD4(bufB, Kb, 12);
    DOT4(bufA, 8);     LD4(bufA, Kb, 16);
    DOT4(bufB, 12);    LD4(bufB, Kb, 20);
    DOT4(bufA, 16);    LD4(bufA, Kb, 24);
    DOT4(bufB, 20);    LD4(bufB, Kb, 28);
    DOT4(bufA, 24);    LD4(bufA, Vb, 0);      // V prefetch starts here
    DOT4(bufB, 28);    LD4(bufB, Vb, 4);

    // ---- 8-lane-group reduce (V batches 0/1 in flight underneath) ----
#pragma unroll
    for (int k = 0; k < K_; ++k) { p0[k] += __shfl_xor(p0[k], 1, 64); p1[k] += __shfl_xor(p1[k], 1, 64); }
#pragma unroll
    for (int k = 0; k < K_; ++k) { p0[k] += __shfl_xor(p0[k], 2, 64); p1[k] += __shfl_xor(p1[k], 2, 64); }
#pragma unroll
    for (int k = 0; k < K_; ++k) { p0[k] += __shfl_xor(p0[k], 4, 64); p1[k] += __shfl_xor(p1[k], 4, 64); }

    // ---- softmax ----
    float mx0 = p0[0], mx1 = p1[0];
#pragma unroll
    for (int k = 1; k < K_; ++k) { mx0 = fmaxf(mx0, p0[k]); mx1 = fmaxf(mx1, p1[k]); }
    float sm0 = 0.f, sm1 = 0.f;
#pragma unroll
    for (int k = 0; k < K_; ++k) {
        p0[k] = __expf(p0[k] - mx0); sm0 += p0[k];
        p1[k] = __expf(p1[k] - mx1); sm1 += p1[k];
    }
    const float in0 = 1.f / sm0, in1 = 1.f / sm1;
#pragma unroll
    for (int k = 0; k < K_; ++k) { p0[k] *= in0; p1[k] *= in1; }

    // ---- attn stores ----
    {
        const int g  = lane >> 3;
        const int kq = lane & 7;
        float* a0 = &attn[(size_t)wrow * (G_ * K_) + g * K_];
        float* a1 = a0 + G_ * K_;
#pragma unroll
        for (int k = 0; k < K_; ++k) {
            if (kq == (k & 7)) { a0[k] = p0[k]; a1[k] = p1[k]; }
        }
    }

    // ---- PV, pipelined ----
    PV4(bufA, 0);   LD4(bufA, Vb, 8);
    PV4(bufB, 4);   LD4(bufB, Vb, 12);
    PV4(bufA, 8);   LD4(bufA, Vb, 16);
    PV4(bufB, 12);  LD4(bufB, Vb, 20);
    PV4(bufA, 16);  LD4(bufA, Vb, 24);
    PV4(bufB, 20);  LD4(bufB, Vb, 28);
    PV4(bufA, 24);
    PV4(bufB, 28);

    *(float4*)&Q[(size_t)wrow * 256 + col]       = o0;   // O aliases Q
    *(float4*)&Q[(size_t)(wrow + 1) * 256 + col] = o1;
#undef LD4
#undef DOT4
#undef PV4
}

// ---------------- Kernel 3: frame = sigmoid(O @ Wl + b) --------------------
__global__ __launch_bounds__(256) void frame_gemm(
    const float* __restrict__ O, const float* __restrict__ Wl,
    const float* __restrict__ bl, float* __restrict__ frame)
{
    __shared__ float O_s[128 * 65];
    __shared__ float Wl_s[64 * 89];

    const int r0 = blockIdx.x * 128;
    const int t  = threadIdx.x;
    const int tm = t >> 3;
    const int tx = t & 7;

    const int lr = t >> 1;
    const int lc = (t & 1) * 32;

    float acc[4][11] = {};

    for (int c0 = 0; c0 < 256; c0 += 64) {
        __syncthreads();
#pragma unroll
        for (int i = 0; i < 8; ++i) {
            float4 v = *(const float4*)&O[(size_t)(r0 + lr) * 256 + c0 + lc + 4 * i];
            *(float4*)&O_s[lr * 65 + lc + 4 * i] = v;
        }
        for (int i = t; i < 64 * 88; i += 256) {
            int c = i / 88;
            int f = i - c * 88;
            Wl_s[c * 89 + f] = Wl[(size_t)c0 * 88 + i];
        }
        __syncthreads();
#pragma unroll
        for (int c = 0; c < 64; ++c) {
            float ov0 = O_s[(4 * tm + 0) * 65 + c];
            float ov1 = O_s[(4 * tm + 1) * 65 + c];
            float ov2 = O_s[(4 * tm + 2) * 65 + c];
            float ov3 = O_s[(4 * tm + 3) * 65 + c];
#pragma unroll
            for (int j = 0; j < 11; ++j) {
                float wv = Wl_s[c * 89 + tx + 8 * j];
                acc[0][j] += ov0 * wv;
                acc[1][j] += ov1 * wv;
                acc[2][j] += ov2 * wv;
                acc[3][j] += ov3 * wv;
            }
        }
    }

#pragma unroll
    for (int i = 0; i < 4; ++i) {
        const size_t row = (size_t)(r0 + 4 * tm + i);
#pragma unroll
        for (int j = 0; j < 11; ++j) {
            const int f = tx + 8 * j;
            float x = acc[i][j] + bl[f];
            frame[row * FOUT + f] = 1.f / (1.f + __expf(-x));
        }
    }
}

extern "C" void kernel_launch(void* const* d_in, const int* in_sizes, int n_in,
                              void* d_out, int out_size, void* d_ws, size_t ws_size,
                              hipStream_t stream) {
    (void)in_sizes; (void)n_in; (void)out_size; (void)ws_size;
    const float* spec = (const float*)d_in[0];
    const float* Wq   = (const float*)d_in[1];
    const float* Wk   = (const float*)d_in[2];
    const float* Wv   = (const float*)d_in[3];
    const float* rel  = (const float*)d_in[4];
    const float* Wl   = (const float*)d_in[5];
    const float* bl   = (const float*)d_in[6];

    float* frame = (float*)d_out;                              // [B,S,88]
    float* attn  = frame + (size_t)B_ * S_ * FOUT;             // [B,S,G,K] (byte 11.53M..44.04M)

    // d_out scratch staging (all dead before the writer of that region runs):
    //  [0 .. 16.78M)   spec_hi   (dead after qkv_mfma)
    //  [16.78 .. 33.55M) spec_lo (dead after qkv_mfma)
    //  [33.55 .. 34.34M) weight splits (dead after qkv_mfma; inside attn region, written before attn)
    //  [0 .. 31.7K)    relT      (written after qkv; read by attn; inside frame region, frame written last)
    bf16*  sh    = (bf16*)d_out;
    bf16*  sl    = sh + (size_t)B_ * S_ * FIN;
    bf16*  bth   = (bf16*)((char*)d_out + 33554432);
    bf16*  btl   = bth + 3 * 65536;
    float* relTd = (float*)d_out;

    float* Q  = (float*)d_ws;                                  // [B*S,256] (becomes O)
    float* Kb = Q  + (size_t)B_ * S_ * C_;
    float* Vb = Kb + (size_t)B_ * S_ * C_;

    split_spec<<<dim3(4096), 256, 0, stream>>>(spec, sh, sl);
    split_w<<<dim3(256, 3), 256, 0, stream>>>(Wq, Wk, Wv, bth, btl);
    qkv_mfma<<<dim3(1536), 256, 0, stream>>>(sh, sl, bth, btl, Q, Kb, Vb);
    rel_transpose<<<dim3(31), 256, 0, stream>>>(rel, relTd);
    attn_wave3<<<dim3(4096), 256, 0, stream>>>(Q, Kb, Vb, relTd, attn);
    frame_gemm<<<dim3(B_ * S_ / 128), 256, 0, stream>>>(Q, Wl, bl, frame);
}

// Round 5
// 157.183 us; speedup vs baseline: 3.1503x; 1.7528x over previous
//
#include <hip/hip_runtime.h>
#include <hip/hip_bf16.h>
#include <math.h>

#define B_   8
#define S_   4096
#define FIN  256
#define C_   256
#define G_   8
#define D_   32
#define K_   31
#define PAD_ 15
#define FOUT 88

typedef __bf16 bf16;
typedef __attribute__((ext_vector_type(8))) __bf16 bf16x8;
typedef __attribute__((ext_vector_type(4))) __bf16 bf16x4;
typedef __attribute__((ext_vector_type(4))) float f32x4;

#define MFMA16(A, B, C) __builtin_amdgcn_mfma_f32_16x16x32_bf16(A, B, C, 0, 0, 0)

// ---------------- Kernel A: split spec fp32 -> bf16 hi/lo ----------------
__global__ __launch_bounds__(256) void split_spec(
    const float* __restrict__ spec, bf16* __restrict__ sh, bf16* __restrict__ sl)
{
    const size_t base = ((size_t)blockIdx.x * 256 + threadIdx.x) * 8;
    float4 x0 = *(const float4*)&spec[base];
    float4 x1 = *(const float4*)&spec[base + 4];
    float xs[8] = {x0.x, x0.y, x0.z, x0.w, x1.x, x1.y, x1.z, x1.w};
    bf16x8 H, L;
#pragma unroll
    for (int j = 0; j < 8; ++j) {
        bf16 h = (bf16)xs[j];
        H[j] = h;
        L[j] = (bf16)(xs[j] - (float)h);
    }
    *(bf16x8*)&sh[base] = H;
    *(bf16x8*)&sl[base] = L;
}

// ---------------- Kernel B: split + transpose weights -> Bt[w][n][k] -------
__global__ void split_w(const float* __restrict__ Wq, const float* __restrict__ Wk,
                        const float* __restrict__ Wv,
                        bf16* __restrict__ bth, bf16* __restrict__ btl)
{
    const int k = blockIdx.x;          // 0..255
    const int w = blockIdx.y;          // 0..2
    const int n = threadIdx.x;         // 0..255
    const float* W = (w == 0) ? Wq : (w == 1) ? Wk : Wv;
    float x = W[(size_t)k * 256 + n];
    bf16 h = (bf16)x;
    bf16 l = (bf16)(x - (float)h);
    size_t o = (size_t)w * 65536 + (size_t)n * 256 + k;
    bth[o] = h;
    btl[o] = l;
}

// ---------------- Kernel C: zero Vt pad zones ------------------------------
// Vt layout: [b][d][4160] bf16 ; element (b,d, 16+t), pads t in [-16,0) and [4096,4144)
__global__ void vt_pad(bf16* __restrict__ Vt) {
    const int idx = blockIdx.x * 256 + threadIdx.x;   // 32768
    const int bd  = idx >> 4;                         // 0..2047
    const int pos = (idx & 15) * 4;                   // 0..60
    const int off = (pos < 16) ? pos : 4096 + pos;    // [0,16) or [4112,4160)
    bf16x4 z = {};
    *(bf16x4*)&Vt[(size_t)bd * 4160 + off] = z;
}

// ---------------- Kernel D: rel -> swizzled bf16 hi/lo planes --------------
// relsG: [hi 16KB][lo 16KB]; plane layout [8 g][32 k][32 d] bf16 with 16B-chunk
// XOR swizzle: chunk' = (d>>3) ^ (k&3). Row k=31 zeroed (pad).
__global__ void rel_prep(const float* __restrict__ rel, char* __restrict__ relsG) {
    const int idx = blockIdx.x * 256 + threadIdx.x;   // 8192
    const int g = idx >> 10, k = (idx >> 5) & 31, d = idx & 31;
    const float v = (k < 31) ? rel[(size_t)(g * 32 + d) * 31 + k] : 0.f;
    bf16 h = (bf16)v;
    bf16 l = (bf16)(v - (float)h);
    const int bo = g * 2048 + k * 64 + (((d >> 3) ^ (k & 3)) << 4) + (d & 7) * 2;
    *(bf16*)(relsG + bo)         = h;
    *(bf16*)(relsG + 16384 + bo) = l;
}

// ---------------- Kernel 1: QKV projection, MFMA split-bf16 ----------------
// Epilogues: Q -> Qh/Ql bf16, K -> Kh/Kl bf16, V -> Vt bf16 transposed+padded.
__device__ __forceinline__ void gload16(const bf16* g, bf16* l) {
    __builtin_amdgcn_global_load_lds(
        (const __attribute__((address_space(1))) void*)g,
        (__attribute__((address_space(3))) void*)l, 16, 0, 0);
}

__device__ __forceinline__ void stage_tile(const bf16* g, bf16* l, int t) {
    const int lg = ((t & 3) ^ ((t >> 3) & 3)) * 8;
    const int r0 = t >> 2;
    const int r1 = 64 + (t >> 2);
    const int u0 = (t & ~63) * 8;
    gload16(g + (size_t)r0 * 256 + lg, l + u0);
    gload16(g + (size_t)r1 * 256 + lg, l + u0 + 2048);
}

__device__ __forceinline__ bf16x8 frag_ld(const bf16* l, int r, int cl) {
    return *(const bf16x8*)&l[r * 32 + ((cl ^ ((r >> 1) & 3)) << 3)];
}

__global__ __launch_bounds__(256) void qkv_mfma(
    const bf16* __restrict__ sh, const bf16* __restrict__ sl,
    const bf16* __restrict__ bth, const bf16* __restrict__ btl,
    bf16* __restrict__ Qh, bf16* __restrict__ Ql,
    bf16* __restrict__ Kh, bf16* __restrict__ Kl,
    bf16* __restrict__ Vt)
{
    __shared__ bf16 lds[4 * 4096];     // Ah | Al | Bh | Bl (8KB each)

    const int t   = threadIdx.x;
    const int swz = ((blockIdx.x & 7) * 192) + (blockIdx.x >> 3);   // 1536 % 8 == 0
    const int mt  = swz / 6, nt = swz % 6;
    const int wt  = nt >> 1;           // 0=Q 1=K 2=V
    const int m0  = mt * 128, n0 = (nt & 1) * 128;
    const bool three = (wt < 2);

    const bf16* ah_g = sh  + (size_t)m0 * 256;
    const bf16* al_g = sl  + (size_t)m0 * 256;
    const bf16* bh_g = bth + (size_t)wt * 65536 + (size_t)n0 * 256;
    const bf16* bl_g = btl + (size_t)wt * 65536 + (size_t)n0 * 256;

    const int lane = t & 63, wid = t >> 6;
    const int wr = (wid >> 1) * 64, wc = (wid & 1) * 64;
    const int fr = lane & 15, cl = lane >> 4;

    f32x4 acc[4][4];
#pragma unroll
    for (int m = 0; m < 4; ++m)
#pragma unroll
        for (int n = 0; n < 4; ++n)
            acc[m][n] = (f32x4){0.f, 0.f, 0.f, 0.f};

    for (int ks = 0; ks < 8; ++ks) {
        const int ko = ks * 32;
        stage_tile(ah_g + ko, lds, t);
        if (three) stage_tile(al_g + ko, lds + 4096, t);
        stage_tile(bh_g + ko, lds + 8192, t);
        stage_tile(bl_g + ko, lds + 12288, t);
        __syncthreads();

        bf16x8 ah[4], bh[4], bl[4];
#pragma unroll
        for (int m = 0; m < 4; ++m) ah[m] = frag_ld(lds, wr + m * 16 + fr, cl);
#pragma unroll
        for (int n = 0; n < 4; ++n) {
            bh[n] = frag_ld(lds + 8192,  wc + n * 16 + fr, cl);
            bl[n] = frag_ld(lds + 12288, wc + n * 16 + fr, cl);
        }
#pragma unroll
        for (int m = 0; m < 4; ++m)
#pragma unroll
            for (int n = 0; n < 4; ++n) {
                acc[m][n] = MFMA16(ah[m], bh[n], acc[m][n]);
                acc[m][n] = MFMA16(ah[m], bl[n], acc[m][n]);
            }
        if (three) {
            bf16x8 al[4];
#pragma unroll
            for (int m = 0; m < 4; ++m) al[m] = frag_ld(lds + 4096, wr + m * 16 + fr, cl);
#pragma unroll
            for (int m = 0; m < 4; ++m)
#pragma unroll
                for (int n = 0; n < 4; ++n)
                    acc[m][n] = MFMA16(al[m], bh[n], acc[m][n]);
        }
        __syncthreads();
    }

    // C/D layout: col = lane&15, row = (lane>>4)*4 + reg
    if (wt < 2) {
        bf16* Oh = (wt == 0) ? Qh : Kh;
        bf16* Ol = (wt == 0) ? Ql : Kl;
#pragma unroll
        for (int m = 0; m < 4; ++m) {
            const int gr = m0 + wr + m * 16 + cl * 4;
#pragma unroll
            for (int n = 0; n < 4; ++n) {
                const int gc = n0 + wc + n * 16 + fr;
#pragma unroll
                for (int i = 0; i < 4; ++i) {
                    const float v = acc[m][n][i];
                    const bf16 hh = (bf16)v;
                    const size_t off = (size_t)(gr + i) * 256 + gc;
                    Oh[off] = hh;
                    Ol[off] = (bf16)(v - (float)hh);
                }
            }
        }
    } else {
#pragma unroll
        for (int m = 0; m < 4; ++m) {
            const int gr = m0 + wr + m * 16 + cl * 4;
            const int bb = gr >> 12, sr = gr & 4095;
#pragma unroll
            for (int n = 0; n < 4; ++n) {
                const int gc = n0 + wc + n * 16 + fr;
                bf16x4 pk;
#pragma unroll
                for (int i = 0; i < 4; ++i) pk[i] = (bf16)acc[m][n][i];
                *(bf16x4*)&Vt[(size_t)(bb * 256 + gc) * 4160 + 16 + sr] = pk;
            }
        }
    }
}

// ---------------- Kernel 2: MFMA windowed attention ------------------------
// Block = 256 thr = 4 waves; each wave = 16 s-rows (strip) x 2 heads.
// Swapped QK^T: C[t][s] over 3 t-tiles of 16. rel bias via rel^T x Q MFMA,
// band-aligned through a per-wave LDS buffer. P reshaped via LDS to PV A-frags.
// V consumed from transposed padded Vt. O stored bf16 over Qh (row-exact alias).
__global__ __launch_bounds__(256) void attn_mfma(
    const bf16* __restrict__ Qh, const bf16* __restrict__ Ql,
    const bf16* __restrict__ Kh, const bf16* __restrict__ Kl,
    const bf16* __restrict__ Vt, const char* __restrict__ relsG,
    float* __restrict__ attn, bf16* __restrict__ Obf)
{
    __shared__ char ldsb[51200];   // rel hi/lo 32K | 4 x Rbuf 2304 | 4 x Pbuf 2304
    const int t = threadIdx.x;

    // stage 32 KB pre-swizzled rel planes
#pragma unroll
    for (int j = 0; j < 8; ++j) {
        const int off = (j * 256 + t) * 16;
        *(uint4*)(ldsb + off) = *(const uint4*)(relsG + off);
    }
    __syncthreads();

    const int wid  = t >> 6;
    const int lane = t & 63;
    const int fr   = lane & 15;     // s-col / frag row
    const int q    = lane >> 4;     // k-chunk group
    const int f7   = fr & 7;

    const int bid2 = ((blockIdx.x & 7) << 8) | (blockIdx.x >> 3);   // 2048 % 8 == 0
    const int sg0  = bid2 << 4;              // global strip base row
    const int b    = sg0 >> 12;
    const int s0   = sg0 & 4095;

    float* Rbuf = (float*)(ldsb + 32768 + wid * 2304);  // [32 k][18 pad] f32
    bf16*  Pbuf = (bf16*) (ldsb + 41984 + wid * 2304);  // [16 s][72 pad] bf16

    {   // zero Pbuf once (valid band positions are rewritten every head)
        uint* p32 = (uint*)Pbuf;
#pragma unroll
        for (int j = 0; j < 9; ++j) p32[lane + 64 * j] = 0u;
    }

    const size_t rowQ = (size_t)(sg0 + fr) * 256;

#pragma unroll
    for (int h = 0; h < 2; ++h) {
        const int g   = wid * 2 + h;
        const int dof = g * 32 + q * 8;

        const bf16x8 qh8 = *(const bf16x8*)&Qh[rowQ + dof];
        const bf16x8 ql8 = *(const bf16x8*)&Ql[rowQ + dof];

        // ---- QK^T tiles: C[t][s], t0 = s0-16+16*tau ----
        f32x4 e0, e1, e2;
#pragma unroll
        for (int tau = 0; tau < 3; ++tau) {
            const int trel = s0 - 16 + tau * 16 + fr;
            bf16x8 kh8 = {}, kl8 = {};
            if ((unsigned)trel < 4096u) {               // OOB rows = 0 (ref pads)
                const size_t rk = ((size_t)(b << 12) + trel) * 256 + dof;
                kh8 = *(const bf16x8*)&Kh[rk];
                kl8 = *(const bf16x8*)&Kl[rk];
            }
            f32x4 a = (f32x4){0.f, 0.f, 0.f, 0.f};
            a = MFMA16(kh8, qh8, a);
            a = MFMA16(kh8, ql8, a);
            a = MFMA16(kl8, qh8, a);
            if (tau == 0) e0 = a; else if (tau == 1) e1 = a; else e2 = a;
        }

        // ---- R[k][s] = rel_g^T . Q_g via MFMA, scattered to Rbuf ----
#pragma unroll
        for (int kap = 0; kap < 2; ++kap) {
            const int krow = kap * 16 + fr;
            const int bo = (g << 11) + krow * 64 + ((q ^ (krow & 3)) << 4);
            const bf16x8 rh8 = *(const bf16x8*)(ldsb + bo);
            const bf16x8 rl8 = *(const bf16x8*)(ldsb + 16384 + bo);
            f32x4 rc = (f32x4){0.f, 0.f, 0.f, 0.f};
            rc = MFMA16(rh8, qh8, rc);
            rc = MFMA16(rh8, ql8, rc);
            rc = MFMA16(rl8, qh8, rc);
#pragma unroll
            for (int r = 0; r < 4; ++r)
                Rbuf[(kap * 16 + q * 4 + r) * 18 + fr] = rc[r];
        }

        // ---- energies: e + R[t-s+15], band mask, softmax over 31 ----
        float ev[3][4];
        float mx = -3.0e38f;
#pragma unroll
        for (int tau = 0; tau < 3; ++tau) {
#pragma unroll
            for (int r = 0; r < 4; ++r) {
                const int rp = q * 4 + r;
                const int kk = tau * 16 + rp - fr - 1;       // window index
                const float eb = (tau == 0) ? e0[r] : (tau == 1) ? e1[r] : e2[r];
                float v = eb + Rbuf[(kk & 31) * 18 + fr];
                const bool valid = (tau == 1) || ((tau == 0) ? (rp > fr) : (rp < fr));
                v = valid ? v : -3.0e38f;
                ev[tau][r] = v;
                mx = fmaxf(mx, v);
            }
        }
        mx = fmaxf(mx, __shfl_xor(mx, 16));
        mx = fmaxf(mx, __shfl_xor(mx, 32));
        float sum = 0.f;
#pragma unroll
        for (int tau = 0; tau < 3; ++tau)
#pragma unroll
            for (int r = 0; r < 4; ++r) {
                const float p = __expf(ev[tau][r] - mx);
                ev[tau][r] = p;
                sum += p;
            }
        sum += __shfl_xor(sum, 16);
        sum += __shfl_xor(sum, 32);
        const float inv = 1.f / sum;

        // ---- attn stores + P -> Pbuf (swizzled chunks) ----
        float* arow = &attn[((size_t)(sg0 + fr) * 8 + g) * 31];
#pragma unroll
        for (int tau = 0; tau < 3; ++tau)
#pragma unroll
            for (int r = 0; r < 4; ++r) {
                const int rp = q * 4 + r;
                const int kk = tau * 16 + rp - fr - 1;
                const bool valid = (tau == 1) || ((tau == 0) ? (rp > fr) : (rp < fr));
                if (valid) {
                    const float p = ev[tau][r] * inv;
                    arow[kk] = p;
                    const int tl = tau * 16 + rp;            // t-local in [0,48)
                    Pbuf[fr * 72 + (((tl >> 3) ^ f7) << 3) + (tl & 7)] = (bf16)p;
                }
            }

        // ---- PV: O[s][d] = P[s][t] . V[t][d] ----
        const bf16x8 a0 = *(const bf16x8*)&Pbuf[fr * 72 + ((q ^ f7) << 3)];
        const bf16x8 a1 = *(const bf16x8*)&Pbuf[fr * 72 + (((4 + q) ^ f7) << 3)];
#pragma unroll
        for (int dl = 0; dl < 2; ++dl) {
            const size_t vrow = (size_t)(b * 256 + g * 32 + dl * 16 + fr) * 4160
                              + s0 + q * 8;                  // = ...*4160 + 16 + (s0-16) + q*8
            const bf16x8 v0 = *(const bf16x8*)&Vt[vrow];
            const bf16x8 v1 = *(const bf16x8*)&Vt[vrow + 32];
            f32x4 o = (f32x4){0.f, 0.f, 0.f, 0.f};
            o = MFMA16(a0, v0, o);
            o = MFMA16(a1, v1, o);
#pragma unroll
            for (int r = 0; r < 4; ++r)
                Obf[(size_t)(sg0 + q * 4 + r) * 256 + g * 32 + dl * 16 + fr] = (bf16)o[r];
        }
    }
}

// ---------------- Kernel 3: frame = sigmoid(O @ Wl + b), O in bf16 ---------
__global__ __launch_bounds__(256) void frame_gemm(
    const bf16* __restrict__ O, const float* __restrict__ Wl,
    const float* __restrict__ bl, float* __restrict__ frame)
{
    __shared__ float O_s[128 * 65];
    __shared__ float Wl_s[64 * 89];

    const int r0 = blockIdx.x * 128;
    const int t  = threadIdx.x;
    const int tm = t >> 3;
    const int tx = t & 7;

    const int lr = t >> 1;
    const int lc = (t & 1) * 32;

    float acc[4][11] = {};

    for (int c0 = 0; c0 < 256; c0 += 64) {
        __syncthreads();
#pragma unroll
        for (int i = 0; i < 4; ++i) {
            bf16x8 v = *(const bf16x8*)&O[(size_t)(r0 + lr) * 256 + c0 + lc + 8 * i];
#pragma unroll
            for (int jj = 0; jj < 8; ++jj)
                O_s[lr * 65 + lc + 8 * i + jj] = (float)v[jj];
        }
        for (int i = t; i < 64 * 88; i += 256) {
            int c = i / 88;
            int f = i - c * 88;
            Wl_s[c * 89 + f] = Wl[(size_t)c0 * 88 + i];
        }
        __syncthreads();
#pragma unroll
        for (int c = 0; c < 64; ++c) {
            float ov0 = O_s[(4 * tm + 0) * 65 + c];
            float ov1 = O_s[(4 * tm + 1) * 65 + c];
            float ov2 = O_s[(4 * tm + 2) * 65 + c];
            float ov3 = O_s[(4 * tm + 3) * 65 + c];
#pragma unroll
            for (int j = 0; j < 11; ++j) {
                float wv = Wl_s[c * 89 + tx + 8 * j];
                acc[0][j] += ov0 * wv;
                acc[1][j] += ov1 * wv;
                acc[2][j] += ov2 * wv;
                acc[3][j] += ov3 * wv;
            }
        }
    }

#pragma unroll
    for (int i = 0; i < 4; ++i) {
        const size_t row = (size_t)(r0 + 4 * tm + i);
#pragma unroll
        for (int j = 0; j < 11; ++j) {
            const int f = tx + 8 * j;
            float x = acc[i][j] + bl[f];
            frame[row * FOUT + f] = 1.f / (1.f + __expf(-x));
        }
    }
}

extern "C" void kernel_launch(void* const* d_in, const int* in_sizes, int n_in,
                              void* d_out, int out_size, void* d_ws, size_t ws_size,
                              hipStream_t stream) {
    (void)in_sizes; (void)n_in; (void)out_size; (void)ws_size;
    const float* spec = (const float*)d_in[0];
    const float* Wq   = (const float*)d_in[1];
    const float* Wk   = (const float*)d_in[2];
    const float* Wv   = (const float*)d_in[3];
    const float* rel  = (const float*)d_in[4];
    const float* Wl   = (const float*)d_in[5];
    const float* bl   = (const float*)d_in[6];

    float* frame = (float*)d_out;                              // [B,S,88]
    float* attn  = frame + (size_t)B_ * S_ * FOUT;             // [B,S,G,K]

    // d_out scratch (dead before the region's writer runs):
    //  sh/sl [0, 33.55M)  : spec splits, dead after qkv
    //  bth/btl @33.55M    : weight splits, dead after qkv (inside attn region)
    //  relsG [0, 32KB)    : written AFTER qkv, read by attn (inside frame region)
    bf16* sh    = (bf16*)d_out;
    bf16* sl    = sh + (size_t)B_ * S_ * FIN;
    bf16* bth   = (bf16*)((char*)d_out + 33554432);
    bf16* btl   = bth + 3 * 65536;
    char* relsG = (char*)d_out;

    // d_ws: Qh | Ql | Kh | Kl | Vt  (O bf16 aliases Qh, row-exact, same-wave)
    bf16* Qh = (bf16*)d_ws;
    bf16* Ql = Qh + (size_t)8388608;
    bf16* Kh = Ql + (size_t)8388608;
    bf16* Kl = Kh + (size_t)8388608;
    bf16* Vt = Kl + (size_t)8388608;          // [8][256][4160] bf16, 17.04 MB

    vt_pad    <<<dim3(128),     256, 0, stream>>>(Vt);
    split_spec<<<dim3(4096),    256, 0, stream>>>(spec, sh, sl);
    split_w   <<<dim3(256, 3),  256, 0, stream>>>(Wq, Wk, Wv, bth, btl);
    qkv_mfma  <<<dim3(1536),    256, 0, stream>>>(sh, sl, bth, btl, Qh, Ql, Kh, Kl, Vt);
    rel_prep  <<<dim3(32),      256, 0, stream>>>(rel, relsG);
    attn_mfma <<<dim3(2048),    256, 0, stream>>>(Qh, Ql, Kh, Kl, Vt, relsG, attn, Qh);
    frame_gemm<<<dim3(256),     256, 0, stream>>>(Qh, Wl, bl, frame);
}

// Round 6
// 129.185 us; speedup vs baseline: 3.8330x; 1.2167x over previous
//
#include <hip/hip_runtime.h>
#include <hip/hip_bf16.h>
#include <math.h>

#define B_   8
#define S_   4096
#define FIN  256
#define C_   256
#define G_   8
#define D_   32
#define K_   31
#define PAD_ 15
#define FOUT 88

typedef __bf16 bf16;
typedef __attribute__((ext_vector_type(8))) __bf16 bf16x8;
typedef __attribute__((ext_vector_type(4))) __bf16 bf16x4;
typedef __attribute__((ext_vector_type(4))) float f32x4;

#define MFMA16(A, B, C) __builtin_amdgcn_mfma_f32_16x16x32_bf16(A, B, C, 0, 0, 0)

// ---------------- Kernel A: split spec fp32 -> bf16 hi/lo ----------------
__global__ __launch_bounds__(256) void split_spec(
    const float* __restrict__ spec, bf16* __restrict__ sh, bf16* __restrict__ sl)
{
    const size_t base = ((size_t)blockIdx.x * 256 + threadIdx.x) * 8;
    float4 x0 = *(const float4*)&spec[base];
    float4 x1 = *(const float4*)&spec[base + 4];
    float xs[8] = {x0.x, x0.y, x0.z, x0.w, x1.x, x1.y, x1.z, x1.w};
    bf16x8 H, L;
#pragma unroll
    for (int j = 0; j < 8; ++j) {
        bf16 h = (bf16)xs[j];
        H[j] = h;
        L[j] = (bf16)(xs[j] - (float)h);
    }
    *(bf16x8*)&sh[base] = H;
    *(bf16x8*)&sl[base] = L;
}

// ---------------- Kernel B: split + transpose weights -> Bt[w][n][k] -------
__global__ void split_w(const float* __restrict__ Wq, const float* __restrict__ Wk,
                        const float* __restrict__ Wv,
                        bf16* __restrict__ bth, bf16* __restrict__ btl)
{
    const int k = blockIdx.x;          // 0..255
    const int w = blockIdx.y;          // 0..2
    const int n = threadIdx.x;         // 0..255
    const float* W = (w == 0) ? Wq : (w == 1) ? Wk : Wv;
    float x = W[(size_t)k * 256 + n];
    bf16 h = (bf16)x;
    bf16 l = (bf16)(x - (float)h);
    size_t o = (size_t)w * 65536 + (size_t)n * 256 + k;
    bth[o] = h;
    btl[o] = l;
}

// ---------------- Kernel B2: split + transpose Wl -> [128 n][256 k] --------
__global__ void split_wl(const float* __restrict__ Wl,
                         bf16* __restrict__ wlh, bf16* __restrict__ wll)
{
    const int k = blockIdx.x;          // 0..255
    const int n = threadIdx.x;         // 0..127 (88 real, rest zero-pad)
    const float x = (n < FOUT) ? Wl[(size_t)k * FOUT + n] : 0.f;
    bf16 h = (bf16)x;
    bf16 l = (bf16)(x - (float)h);
    wlh[(size_t)n * 256 + k] = h;
    wll[(size_t)n * 256 + k] = l;
}

// ---------------- Kernel C: zero Vt pad zones ------------------------------
// Vt layout: [b][d][4160] bf16 ; element (b,d, 16+t), pads t in [-16,0) and [4096,4144)
__global__ void vt_pad(bf16* __restrict__ Vt) {
    const int idx = blockIdx.x * 256 + threadIdx.x;   // 32768
    const int bd  = idx >> 4;                         // 0..2047
    const int pos = (idx & 15) * 4;                   // 0..60
    const int off = (pos < 16) ? pos : 4096 + pos;    // [0,16) or [4112,4160)
    bf16x4 z = {};
    *(bf16x4*)&Vt[(size_t)bd * 4160 + off] = z;
}

// ---------------- Kernel D: rel -> swizzled bf16 hi/lo planes --------------
__global__ void rel_prep(const float* __restrict__ rel, char* __restrict__ relsG) {
    const int idx = blockIdx.x * 256 + threadIdx.x;   // 8192
    const int g = idx >> 10, k = (idx >> 5) & 31, d = idx & 31;
    const float v = (k < 31) ? rel[(size_t)(g * 32 + d) * 31 + k] : 0.f;
    bf16 h = (bf16)v;
    bf16 l = (bf16)(v - (float)h);
    const int bo = g * 2048 + k * 64 + (((d >> 3) ^ (k & 3)) << 4) + (d & 7) * 2;
    *(bf16*)(relsG + bo)         = h;
    *(bf16*)(relsG + 16384 + bo) = l;
}

// ---------------- shared helpers: staged swizzled tiles --------------------
__device__ __forceinline__ void gload16(const bf16* g, bf16* l) {
    __builtin_amdgcn_global_load_lds(
        (const __attribute__((address_space(1))) void*)g,
        (__attribute__((address_space(3))) void*)l, 16, 0, 0);
}

__device__ __forceinline__ void stage_tile(const bf16* g, bf16* l, int t) {
    const int lg = ((t & 3) ^ ((t >> 3) & 3)) * 8;
    const int r0 = t >> 2;
    const int r1 = 64 + (t >> 2);
    const int u0 = (t & ~63) * 8;
    gload16(g + (size_t)r0 * 256 + lg, l + u0);
    gload16(g + (size_t)r1 * 256 + lg, l + u0 + 2048);
}

__device__ __forceinline__ bf16x8 frag_ld(const bf16* l, int r, int cl) {
    return *(const bf16x8*)&l[r * 32 + ((cl ^ ((r >> 1) & 3)) << 3)];
}

// ---------------- Kernel 1: QKV projection, MFMA split-bf16 ----------------
__global__ __launch_bounds__(256) void qkv_mfma(
    const bf16* __restrict__ sh, const bf16* __restrict__ sl,
    const bf16* __restrict__ bth, const bf16* __restrict__ btl,
    bf16* __restrict__ Qh, bf16* __restrict__ Ql,
    bf16* __restrict__ Kh, bf16* __restrict__ Kl,
    bf16* __restrict__ Vt)
{
    __shared__ bf16 lds[4 * 4096];     // Ah | Al | Bh | Bl (8KB each)

    const int t   = threadIdx.x;
    const int swz = ((blockIdx.x & 7) * 192) + (blockIdx.x >> 3);   // 1536 % 8 == 0
    const int mt  = swz / 6, nt = swz % 6;
    const int wt  = nt >> 1;           // 0=Q 1=K 2=V
    const int m0  = mt * 128, n0 = (nt & 1) * 128;
    const bool three = (wt < 2);

    const bf16* ah_g = sh  + (size_t)m0 * 256;
    const bf16* al_g = sl  + (size_t)m0 * 256;
    const bf16* bh_g = bth + (size_t)wt * 65536 + (size_t)n0 * 256;
    const bf16* bl_g = btl + (size_t)wt * 65536 + (size_t)n0 * 256;

    const int lane = t & 63, wid = t >> 6;
    const int wr = (wid >> 1) * 64, wc = (wid & 1) * 64;
    const int fr = lane & 15, cl = lane >> 4;

    f32x4 acc[4][4];
#pragma unroll
    for (int m = 0; m < 4; ++m)
#pragma unroll
        for (int n = 0; n < 4; ++n)
            acc[m][n] = (f32x4){0.f, 0.f, 0.f, 0.f};

    for (int ks = 0; ks < 8; ++ks) {
        const int ko = ks * 32;
        stage_tile(ah_g + ko, lds, t);
        if (three) stage_tile(al_g + ko, lds + 4096, t);
        stage_tile(bh_g + ko, lds + 8192, t);
        stage_tile(bl_g + ko, lds + 12288, t);
        __syncthreads();

        bf16x8 ah[4], bh[4], bl[4];
#pragma unroll
        for (int m = 0; m < 4; ++m) ah[m] = frag_ld(lds, wr + m * 16 + fr, cl);
#pragma unroll
        for (int n = 0; n < 4; ++n) {
            bh[n] = frag_ld(lds + 8192,  wc + n * 16 + fr, cl);
            bl[n] = frag_ld(lds + 12288, wc + n * 16 + fr, cl);
        }
#pragma unroll
        for (int m = 0; m < 4; ++m)
#pragma unroll
            for (int n = 0; n < 4; ++n) {
                acc[m][n] = MFMA16(ah[m], bh[n], acc[m][n]);
                acc[m][n] = MFMA16(ah[m], bl[n], acc[m][n]);
            }
        if (three) {
            bf16x8 al[4];
#pragma unroll
            for (int m = 0; m < 4; ++m) al[m] = frag_ld(lds + 4096, wr + m * 16 + fr, cl);
#pragma unroll
            for (int m = 0; m < 4; ++m)
#pragma unroll
                for (int n = 0; n < 4; ++n)
                    acc[m][n] = MFMA16(al[m], bh[n], acc[m][n]);
        }
        __syncthreads();
    }

    // C/D layout: col = lane&15, row = (lane>>4)*4 + reg
    if (wt < 2) {
        bf16* Oh = (wt == 0) ? Qh : Kh;
        bf16* Ol = (wt == 0) ? Ql : Kl;
#pragma unroll
        for (int m = 0; m < 4; ++m) {
            const int gr = m0 + wr + m * 16 + cl * 4;
#pragma unroll
            for (int n = 0; n < 4; ++n) {
                const int gc = n0 + wc + n * 16 + fr;
#pragma unroll
                for (int i = 0; i < 4; ++i) {
                    const float v = acc[m][n][i];
                    const bf16 hh = (bf16)v;
                    const size_t off = (size_t)(gr + i) * 256 + gc;
                    Oh[off] = hh;
                    Ol[off] = (bf16)(v - (float)hh);
                }
            }
        }
    } else {
#pragma unroll
        for (int m = 0; m < 4; ++m) {
            const int gr = m0 + wr + m * 16 + cl * 4;
            const int bb = gr >> 12, sr = gr & 4095;
#pragma unroll
            for (int n = 0; n < 4; ++n) {
                const int gc = n0 + wc + n * 16 + fr;
                bf16x4 pk;
#pragma unroll
                for (int i = 0; i < 4; ++i) pk[i] = (bf16)acc[m][n][i];
                *(bf16x4*)&Vt[(size_t)(bb * 256 + gc) * 4160 + 16 + sr] = pk;
            }
        }
    }
}

// ---------------- Kernel 2: MFMA windowed attention ------------------------
__global__ __launch_bounds__(256) void attn_mfma(
    const bf16* __restrict__ Qh, const bf16* __restrict__ Ql,
    const bf16* __restrict__ Kh, const bf16* __restrict__ Kl,
    const bf16* __restrict__ Vt, const char* __restrict__ relsG,
    float* __restrict__ attn, bf16* __restrict__ Obf)
{
    __shared__ char ldsb[51200];   // rel hi/lo 32K | 4 x Rbuf 2304 | 4 x Pbuf 2304
    const int t = threadIdx.x;

#pragma unroll
    for (int j = 0; j < 8; ++j) {
        const int off = (j * 256 + t) * 16;
        *(uint4*)(ldsb + off) = *(const uint4*)(relsG + off);
    }
    __syncthreads();

    const int wid  = t >> 6;
    const int lane = t & 63;
    const int fr   = lane & 15;     // s-col / frag row
    const int q    = lane >> 4;     // k-chunk group
    const int f7   = fr & 7;

    const int bid2 = ((blockIdx.x & 7) << 8) | (blockIdx.x >> 3);   // 2048 % 8 == 0
    const int sg0  = bid2 << 4;
    const int b    = sg0 >> 12;
    const int s0   = sg0 & 4095;

    float* Rbuf = (float*)(ldsb + 32768 + wid * 2304);  // [32 k][18 pad] f32
    bf16*  Pbuf = (bf16*) (ldsb + 41984 + wid * 2304);  // [16 s][72 pad] bf16

    {
        uint* p32 = (uint*)Pbuf;
#pragma unroll
        for (int j = 0; j < 9; ++j) p32[lane + 64 * j] = 0u;
    }

    const size_t rowQ = (size_t)(sg0 + fr) * 256;

#pragma unroll
    for (int h = 0; h < 2; ++h) {
        const int g   = wid * 2 + h;
        const int dof = g * 32 + q * 8;

        const bf16x8 qh8 = *(const bf16x8*)&Qh[rowQ + dof];
        const bf16x8 ql8 = *(const bf16x8*)&Ql[rowQ + dof];

        f32x4 e0, e1, e2;
#pragma unroll
        for (int tau = 0; tau < 3; ++tau) {
            const int trel = s0 - 16 + tau * 16 + fr;
            bf16x8 kh8 = {}, kl8 = {};
            if ((unsigned)trel < 4096u) {
                const size_t rk = ((size_t)(b << 12) + trel) * 256 + dof;
                kh8 = *(const bf16x8*)&Kh[rk];
                kl8 = *(const bf16x8*)&Kl[rk];
            }
            f32x4 a = (f32x4){0.f, 0.f, 0.f, 0.f};
            a = MFMA16(kh8, qh8, a);
            a = MFMA16(kh8, ql8, a);
            a = MFMA16(kl8, qh8, a);
            if (tau == 0) e0 = a; else if (tau == 1) e1 = a; else e2 = a;
        }

#pragma unroll
        for (int kap = 0; kap < 2; ++kap) {
            const int krow = kap * 16 + fr;
            const int bo = (g << 11) + krow * 64 + ((q ^ (krow & 3)) << 4);
            const bf16x8 rh8 = *(const bf16x8*)(ldsb + bo);
            const bf16x8 rl8 = *(const bf16x8*)(ldsb + 16384 + bo);
            f32x4 rc = (f32x4){0.f, 0.f, 0.f, 0.f};
            rc = MFMA16(rh8, qh8, rc);
            rc = MFMA16(rh8, ql8, rc);
            rc = MFMA16(rl8, qh8, rc);
#pragma unroll
            for (int r = 0; r < 4; ++r)
                Rbuf[(kap * 16 + q * 4 + r) * 18 + fr] = rc[r];
        }

        float ev[3][4];
        float mx = -3.0e38f;
#pragma unroll
        for (int tau = 0; tau < 3; ++tau) {
#pragma unroll
            for (int r = 0; r < 4; ++r) {
                const int rp = q * 4 + r;
                const int kk = tau * 16 + rp - fr - 1;
                const float eb = (tau == 0) ? e0[r] : (tau == 1) ? e1[r] : e2[r];
                float v = eb + Rbuf[(kk & 31) * 18 + fr];
                const bool valid = (tau == 1) || ((tau == 0) ? (rp > fr) : (rp < fr));
                v = valid ? v : -3.0e38f;
                ev[tau][r] = v;
                mx = fmaxf(mx, v);
            }
        }
        mx = fmaxf(mx, __shfl_xor(mx, 16));
        mx = fmaxf(mx, __shfl_xor(mx, 32));
        float sum = 0.f;
#pragma unroll
        for (int tau = 0; tau < 3; ++tau)
#pragma unroll
            for (int r = 0; r < 4; ++r) {
                const float p = __expf(ev[tau][r] - mx);
                ev[tau][r] = p;
                sum += p;
            }
        sum += __shfl_xor(sum, 16);
        sum += __shfl_xor(sum, 32);
        const float inv = 1.f / sum;

        float* arow = &attn[((size_t)(sg0 + fr) * 8 + g) * 31];
#pragma unroll
        for (int tau = 0; tau < 3; ++tau)
#pragma unroll
            for (int r = 0; r < 4; ++r) {
                const int rp = q * 4 + r;
                const int kk = tau * 16 + rp - fr - 1;
                const bool valid = (tau == 1) || ((tau == 0) ? (rp > fr) : (rp < fr));
                if (valid) {
                    const float p = ev[tau][r] * inv;
                    arow[kk] = p;
                    const int tl = tau * 16 + rp;
                    Pbuf[fr * 72 + (((tl >> 3) ^ f7) << 3) + (tl & 7)] = (bf16)p;
                }
            }

        const bf16x8 a0 = *(const bf16x8*)&Pbuf[fr * 72 + ((q ^ f7) << 3)];
        const bf16x8 a1 = *(const bf16x8*)&Pbuf[fr * 72 + (((4 + q) ^ f7) << 3)];
#pragma unroll
        for (int dl = 0; dl < 2; ++dl) {
            const size_t vrow = (size_t)(b * 256 + g * 32 + dl * 16 + fr) * 4160
                              + s0 + q * 8;
            const bf16x8 v0 = *(const bf16x8*)&Vt[vrow];
            const bf16x8 v1 = *(const bf16x8*)&Vt[vrow + 32];
            f32x4 o = (f32x4){0.f, 0.f, 0.f, 0.f};
            o = MFMA16(a0, v0, o);
            o = MFMA16(a1, v1, o);
#pragma unroll
            for (int r = 0; r < 4; ++r)
                Obf[(size_t)(sg0 + q * 4 + r) * 256 + g * 32 + dl * 16 + fr] = (bf16)o[r];
        }
    }
}

// ---------------- Kernel 3: frame = sigmoid(O @ WlT + b), MFMA -------------
// A = O bf16 [32768][256]; B = WlT hi/lo [128 n][256 k] (n>=88 zero).
// Same 128x128 / BK=32 structure as qkv_mfma, 2-term (Ah*Bh + Ah*Bl).
__global__ __launch_bounds__(256) void frame_mfma(
    const bf16* __restrict__ O,
    const bf16* __restrict__ wlh, const bf16* __restrict__ wll,
    const float* __restrict__ bl, float* __restrict__ frame)
{
    __shared__ bf16 lds[3 * 4096];     // Ah | Bh | Bl

    const int t  = threadIdx.x;
    const int m0 = blockIdx.x * 128;

    const bf16* a_g = O + (size_t)m0 * 256;

    const int lane = t & 63, wid = t >> 6;
    const int wr = (wid >> 1) * 64, wc = (wid & 1) * 64;
    const int fr = lane & 15, cl = lane >> 4;

    f32x4 acc[4][4];
#pragma unroll
    for (int m = 0; m < 4; ++m)
#pragma unroll
        for (int n = 0; n < 4; ++n)
            acc[m][n] = (f32x4){0.f, 0.f, 0.f, 0.f};

    for (int ks = 0; ks < 8; ++ks) {
        const int ko = ks * 32;
        stage_tile(a_g + ko, lds, t);
        stage_tile(wlh + ko, lds + 4096, t);
        stage_tile(wll + ko, lds + 8192, t);
        __syncthreads();

        bf16x8 ah[4], bh[4], bl4[4];
#pragma unroll
        for (int m = 0; m < 4; ++m) ah[m] = frag_ld(lds, wr + m * 16 + fr, cl);
#pragma unroll
        for (int n = 0; n < 4; ++n) {
            bh[n]  = frag_ld(lds + 4096, wc + n * 16 + fr, cl);
            bl4[n] = frag_ld(lds + 8192, wc + n * 16 + fr, cl);
        }
#pragma unroll
        for (int m = 0; m < 4; ++m)
#pragma unroll
            for (int n = 0; n < 4; ++n) {
                acc[m][n] = MFMA16(ah[m], bh[n],  acc[m][n]);
                acc[m][n] = MFMA16(ah[m], bl4[n], acc[m][n]);
            }
        __syncthreads();
    }

#pragma unroll
    for (int m = 0; m < 4; ++m) {
        const int gr = m0 + wr + m * 16 + cl * 4;
#pragma unroll
        for (int n = 0; n < 4; ++n) {
            const int gc = wc + n * 16 + fr;
            if (gc < FOUT) {
                const float bb = bl[gc];
#pragma unroll
                for (int i = 0; i < 4; ++i) {
                    const float x = acc[m][n][i] + bb;
                    frame[(size_t)(gr + i) * FOUT + gc] = 1.f / (1.f + __expf(-x));
                }
            }
        }
    }
}

extern "C" void kernel_launch(void* const* d_in, const int* in_sizes, int n_in,
                              void* d_out, int out_size, void* d_ws, size_t ws_size,
                              hipStream_t stream) {
    (void)in_sizes; (void)n_in; (void)out_size; (void)ws_size;
    const float* spec = (const float*)d_in[0];
    const float* Wq   = (const float*)d_in[1];
    const float* Wk   = (const float*)d_in[2];
    const float* Wv   = (const float*)d_in[3];
    const float* rel  = (const float*)d_in[4];
    const float* Wl   = (const float*)d_in[5];
    const float* bl   = (const float*)d_in[6];

    float* frame = (float*)d_out;                              // [B,S,88]
    float* attn  = frame + (size_t)B_ * S_ * FOUT;             // [B,S,G,K]

    // d_out scratch (dead before the region's writer runs):
    bf16* sh    = (bf16*)d_out;
    bf16* sl    = sh + (size_t)B_ * S_ * FIN;
    bf16* bth   = (bf16*)((char*)d_out + 33554432);
    bf16* btl   = bth + 3 * 65536;
    char* relsG = (char*)d_out;

    // d_ws: Qh | Ql | Kh | Kl | Vt | WlT (O bf16 aliases Qh, row-exact, same-wave)
    bf16* Qh  = (bf16*)d_ws;
    bf16* Ql  = Qh + (size_t)8388608;
    bf16* Kh  = Ql + (size_t)8388608;
    bf16* Kl  = Kh + (size_t)8388608;
    bf16* Vt  = Kl + (size_t)8388608;          // [8][256][4160] bf16, 17.04 MB
    bf16* wlh = Vt + (size_t)8 * 256 * 4160;   // [128][256]
    bf16* wll = wlh + 128 * 256;

    vt_pad    <<<dim3(128),     256, 0, stream>>>(Vt);
    split_spec<<<dim3(4096),    256, 0, stream>>>(spec, sh, sl);
    split_w   <<<dim3(256, 3),  256, 0, stream>>>(Wq, Wk, Wv, bth, btl);
    split_wl  <<<dim3(256),     128, 0, stream>>>(Wl, wlh, wll);
    qkv_mfma  <<<dim3(1536),    256, 0, stream>>>(sh, sl, bth, btl, Qh, Ql, Kh, Kl, Vt);
    rel_prep  <<<dim3(32),      256, 0, stream>>>(rel, relsG);
    attn_mfma <<<dim3(2048),    256, 0, stream>>>(Qh, Ql, Kh, Kl, Vt, relsG, attn, Qh);
    frame_mfma<<<dim3(256),     256, 0, stream>>>(Qh, wlh, wll, bl, frame);
}

// Round 7
// 128.541 us; speedup vs baseline: 3.8522x; 1.0050x over previous
//
#include <hip/hip_runtime.h>
#include <hip/hip_bf16.h>
#include <math.h>

#define B_   8
#define S_   4096
#define FIN  256
#define C_   256
#define G_   8
#define D_   32
#define K_   31
#define PAD_ 15
#define FOUT 88

typedef __bf16 bf16;
typedef __attribute__((ext_vector_type(8))) __bf16 bf16x8;
typedef __attribute__((ext_vector_type(4))) __bf16 bf16x4;
typedef __attribute__((ext_vector_type(4))) float f32x4;

#define MFMA16(A, B, C) __builtin_amdgcn_mfma_f32_16x16x32_bf16(A, B, C, 0, 0, 0)

// ---------------- Kernel A: split spec fp32 -> bf16 hi/lo ----------------
__global__ __launch_bounds__(256) void split_spec(
    const float* __restrict__ spec, bf16* __restrict__ sh, bf16* __restrict__ sl)
{
    const size_t base = ((size_t)blockIdx.x * 256 + threadIdx.x) * 8;
    float4 x0 = *(const float4*)&spec[base];
    float4 x1 = *(const float4*)&spec[base + 4];
    float xs[8] = {x0.x, x0.y, x0.z, x0.w, x1.x, x1.y, x1.z, x1.w};
    bf16x8 H, L;
#pragma unroll
    for (int j = 0; j < 8; ++j) {
        bf16 h = (bf16)xs[j];
        H[j] = h;
        L[j] = (bf16)(xs[j] - (float)h);
    }
    *(bf16x8*)&sh[base] = H;
    *(bf16x8*)&sl[base] = L;
}

// ---------------- Kernel B: split + transpose weights -> Bt[w][n][k] -------
__global__ void split_w(const float* __restrict__ Wq, const float* __restrict__ Wk,
                        const float* __restrict__ Wv,
                        bf16* __restrict__ bth, bf16* __restrict__ btl)
{
    const int k = blockIdx.x;          // 0..255
    const int w = blockIdx.y;          // 0..2
    const int n = threadIdx.x;         // 0..255
    const float* W = (w == 0) ? Wq : (w == 1) ? Wk : Wv;
    float x = W[(size_t)k * 256 + n];
    bf16 h = (bf16)x;
    bf16 l = (bf16)(x - (float)h);
    size_t o = (size_t)w * 65536 + (size_t)n * 256 + k;
    bth[o] = h;
    btl[o] = l;
}

// ---------------- Kernel B2: split + transpose Wl -> [128 n][256 k] --------
__global__ void split_wl(const float* __restrict__ Wl,
                         bf16* __restrict__ wlh, bf16* __restrict__ wll)
{
    const int k = blockIdx.x;          // 0..255
    const int n = threadIdx.x;         // 0..127 (88 real, rest zero-pad)
    const float x = (n < FOUT) ? Wl[(size_t)k * FOUT + n] : 0.f;
    bf16 h = (bf16)x;
    bf16 l = (bf16)(x - (float)h);
    wlh[(size_t)n * 256 + k] = h;
    wll[(size_t)n * 256 + k] = l;
}

// ---------------- Kernel C: zero Vt pad zones ------------------------------
__global__ void vt_pad(bf16* __restrict__ Vt) {
    const int idx = blockIdx.x * 256 + threadIdx.x;   // 32768
    const int bd  = idx >> 4;                         // 0..2047
    const int pos = (idx & 15) * 4;                   // 0..60
    const int off = (pos < 16) ? pos : 4096 + pos;    // [0,16) or [4112,4160)
    bf16x4 z = {};
    *(bf16x4*)&Vt[(size_t)bd * 4160 + off] = z;
}

// ---------------- Kernel D: rel -> plain bf16 hi/lo planes [8][32][32] -----
// Row k=31 zeroed (pad). Read directly from global by attn (L2-resident).
__global__ void rel_prep(const float* __restrict__ rel,
                         bf16* __restrict__ relH, bf16* __restrict__ relL) {
    const int idx = blockIdx.x * 256 + threadIdx.x;   // 8192
    const int g = idx >> 10, k = (idx >> 5) & 31, d = idx & 31;
    const float v = (k < 31) ? rel[(size_t)(g * 32 + d) * 31 + k] : 0.f;
    bf16 h = (bf16)v;
    relH[idx] = h;
    relL[idx] = (bf16)(v - (float)h);
}

// ---------------- shared helpers: staged swizzled tiles --------------------
__device__ __forceinline__ void gload16(const bf16* g, bf16* l) {
    __builtin_amdgcn_global_load_lds(
        (const __attribute__((address_space(1))) void*)g,
        (__attribute__((address_space(3))) void*)l, 16, 0, 0);
}

__device__ __forceinline__ void stage_tile(const bf16* g, bf16* l, int t) {
    const int lg = ((t & 3) ^ ((t >> 3) & 3)) * 8;
    const int r0 = t >> 2;
    const int r1 = 64 + (t >> 2);
    const int u0 = (t & ~63) * 8;
    gload16(g + (size_t)r0 * 256 + lg, l + u0);
    gload16(g + (size_t)r1 * 256 + lg, l + u0 + 2048);
}

__device__ __forceinline__ bf16x8 frag_ld(const bf16* l, int r, int cl) {
    return *(const bf16x8*)&l[r * 32 + ((cl ^ ((r >> 1) & 3)) << 3)];
}

// ---------------- Kernel 1: QKV projection, MFMA split-bf16, 2-phase dbuf --
__global__ __launch_bounds__(256) void qkv_mfma(
    const bf16* __restrict__ sh, const bf16* __restrict__ sl,
    const bf16* __restrict__ bth, const bf16* __restrict__ btl,
    bf16* __restrict__ Qh, bf16* __restrict__ Ql,
    bf16* __restrict__ Kh, bf16* __restrict__ Kl,
    bf16* __restrict__ Vt)
{
    __shared__ bf16 lds[2 * 4 * 4096];   // 2 bufs x (Ah|Al|Bh|Bl), 64 KB

    const int t   = threadIdx.x;
    const int swz = ((blockIdx.x & 7) * 192) + (blockIdx.x >> 3);   // 1536 % 8 == 0
    const int mt  = swz / 6, nt = swz % 6;
    const int wt  = nt >> 1;           // 0=Q 1=K 2=V
    const int m0  = mt * 128, n0 = (nt & 1) * 128;
    const bool three = (wt < 2);

    const bf16* ah_g = sh  + (size_t)m0 * 256;
    const bf16* al_g = sl  + (size_t)m0 * 256;
    const bf16* bh_g = bth + (size_t)wt * 65536 + (size_t)n0 * 256;
    const bf16* bl_g = btl + (size_t)wt * 65536 + (size_t)n0 * 256;

    const int lane = t & 63, wid = t >> 6;
    const int wr = (wid >> 1) * 64, wc = (wid & 1) * 64;
    const int fr = lane & 15, cl = lane >> 4;

    f32x4 acc[4][4];
#pragma unroll
    for (int m = 0; m < 4; ++m)
#pragma unroll
        for (int n = 0; n < 4; ++n)
            acc[m][n] = (f32x4){0.f, 0.f, 0.f, 0.f};

    // prologue: stage K-step 0 into buf 0
    stage_tile(ah_g, lds, t);
    if (three) stage_tile(al_g, lds + 4096, t);
    stage_tile(bh_g, lds + 8192, t);
    stage_tile(bl_g, lds + 12288, t);
    __syncthreads();

    for (int ks = 0; ks < 8; ++ks) {
        const int cur = (ks & 1) * 16384;
        if (ks < 7) {                      // prefetch next K-step into other buf
            const int nxt = 16384 - cur;
            const int ko  = (ks + 1) * 32;
            stage_tile(ah_g + ko, lds + nxt, t);
            if (three) stage_tile(al_g + ko, lds + nxt + 4096, t);
            stage_tile(bh_g + ko, lds + nxt + 8192, t);
            stage_tile(bl_g + ko, lds + nxt + 12288, t);
        }

        bf16x8 ah[4], bh[4], bl[4];
#pragma unroll
        for (int m = 0; m < 4; ++m) ah[m] = frag_ld(lds + cur, wr + m * 16 + fr, cl);
#pragma unroll
        for (int n = 0; n < 4; ++n) {
            bh[n] = frag_ld(lds + cur + 8192,  wc + n * 16 + fr, cl);
            bl[n] = frag_ld(lds + cur + 12288, wc + n * 16 + fr, cl);
        }
#pragma unroll
        for (int m = 0; m < 4; ++m)
#pragma unroll
            for (int n = 0; n < 4; ++n) {
                acc[m][n] = MFMA16(ah[m], bh[n], acc[m][n]);
                acc[m][n] = MFMA16(ah[m], bl[n], acc[m][n]);
            }
        if (three) {
            bf16x8 al[4];
#pragma unroll
            for (int m = 0; m < 4; ++m) al[m] = frag_ld(lds + cur + 4096, wr + m * 16 + fr, cl);
#pragma unroll
            for (int m = 0; m < 4; ++m)
#pragma unroll
                for (int n = 0; n < 4; ++n)
                    acc[m][n] = MFMA16(al[m], bh[n], acc[m][n]);
        }
        __syncthreads();   // drains prefetch (vmcnt 0) + guards buf reuse
    }

    // C/D layout: col = lane&15, row = (lane>>4)*4 + reg
    if (wt < 2) {
        bf16* Oh = (wt == 0) ? Qh : Kh;
        bf16* Ol = (wt == 0) ? Ql : Kl;
#pragma unroll
        for (int m = 0; m < 4; ++m) {
            const int gr = m0 + wr + m * 16 + cl * 4;
#pragma unroll
            for (int n = 0; n < 4; ++n) {
                const int gc = n0 + wc + n * 16 + fr;
#pragma unroll
                for (int i = 0; i < 4; ++i) {
                    const float v = acc[m][n][i];
                    const bf16 hh = (bf16)v;
                    const size_t off = (size_t)(gr + i) * 256 + gc;
                    Oh[off] = hh;
                    Ol[off] = (bf16)(v - (float)hh);
                }
            }
        }
    } else {
#pragma unroll
        for (int m = 0; m < 4; ++m) {
            const int gr = m0 + wr + m * 16 + cl * 4;
            const int bb = gr >> 12, sr = gr & 4095;
#pragma unroll
            for (int n = 0; n < 4; ++n) {
                const int gc = n0 + wc + n * 16 + fr;
                bf16x4 pk;
#pragma unroll
                for (int i = 0; i < 4; ++i) pk[i] = (bf16)acc[m][n][i];
                *(bf16x4*)&Vt[(size_t)(bb * 256 + gc) * 4160 + 16 + sr] = pk;
            }
        }
    }
}

// ---------------- Kernel 2: MFMA windowed attention (no-barrier version) ---
// Per wave: 16 s-rows x 2 heads. rel A-frags loaded straight from global
// (L2-resident). LDS = per-wave Rbuf(2304B, reused as Pf32 for coalesced attn
// writeback) + Pbuf(2304B). PV uses swapped operands -> C[d][s] -> bf16x4
// vector O stores. No __syncthreads anywhere.
__global__ __launch_bounds__(256) void attn_mfma(
    const bf16* __restrict__ Qh, const bf16* __restrict__ Ql,
    const bf16* __restrict__ Kh, const bf16* __restrict__ Kl,
    const bf16* __restrict__ Vt,
    const bf16* __restrict__ relH, const bf16* __restrict__ relL,
    float* __restrict__ attn, bf16* __restrict__ Obf)
{
    __shared__ char ldsb[18432];   // 4 waves x (Rbuf/Pf32 2304 | Pbuf 2304)

    const int t    = threadIdx.x;
    const int wid  = t >> 6;
    const int lane = t & 63;
    const int fr   = lane & 15;     // s-col / frag row
    const int q    = lane >> 4;     // k-chunk group
    const int f7   = fr & 7;
    const int sl   = lane >> 2;     // writeback row 0..15
    const int jj   = lane & 3;

    const int bid2 = ((blockIdx.x & 7) << 8) | (blockIdx.x >> 3);   // 2048 % 8 == 0
    const int sg0  = bid2 << 4;
    const int b    = sg0 >> 12;
    const int s0   = sg0 & 4095;

    float* Rbuf = (float*)(ldsb + wid * 4608);          // [32 k][18] f32
    float* Pf32 = Rbuf;                                 // reused: [16 s][36] f32
    bf16*  Pbuf = (bf16*) (ldsb + wid * 4608 + 2304);   // [16 s][72] bf16

    {   // zero Pbuf once (valid band positions rewritten every head)
        uint* p32 = (uint*)Pbuf;
#pragma unroll
        for (int j = 0; j < 9; ++j) p32[lane + 64 * j] = 0u;
    }

    const size_t rowQ = (size_t)(sg0 + fr) * 256;

#pragma unroll
    for (int h = 0; h < 2; ++h) {
        asm volatile("" ::: "memory");
        const int g   = wid * 2 + h;
        const int dof = g * 32 + q * 8;

        const bf16x8 qh8 = *(const bf16x8*)&Qh[rowQ + dof];
        const bf16x8 ql8 = *(const bf16x8*)&Ql[rowQ + dof];

        // ---- QK^T tiles: C[t][s], t0 = s0-16+16*tau ----
        f32x4 e0, e1, e2;
#pragma unroll
        for (int tau = 0; tau < 3; ++tau) {
            const int trel = s0 - 16 + tau * 16 + fr;
            bf16x8 kh8 = {}, kl8 = {};
            if ((unsigned)trel < 4096u) {
                const size_t rk = ((size_t)(b << 12) + trel) * 256 + dof;
                kh8 = *(const bf16x8*)&Kh[rk];
                kl8 = *(const bf16x8*)&Kl[rk];
            }
            f32x4 a = (f32x4){0.f, 0.f, 0.f, 0.f};
            a = MFMA16(kh8, qh8, a);
            a = MFMA16(kh8, ql8, a);
            a = MFMA16(kl8, qh8, a);
            if (tau == 0) e0 = a; else if (tau == 1) e1 = a; else e2 = a;
        }

        // ---- R[k][s] = rel_g^T . Q_g ; A-frags straight from global ----
#pragma unroll
        for (int kap = 0; kap < 2; ++kap) {
            const size_t ro = (size_t)(g * 32 + kap * 16 + fr) * 32 + q * 8;
            const bf16x8 rh8 = *(const bf16x8*)&relH[ro];
            const bf16x8 rl8 = *(const bf16x8*)&relL[ro];
            f32x4 rc = (f32x4){0.f, 0.f, 0.f, 0.f};
            rc = MFMA16(rh8, qh8, rc);
            rc = MFMA16(rh8, ql8, rc);
            rc = MFMA16(rl8, qh8, rc);
#pragma unroll
            for (int r = 0; r < 4; ++r)
                Rbuf[(kap * 16 + q * 4 + r) * 18 + fr] = rc[r];
        }

        // ---- energies: e + R[t-s+15], band mask, softmax over 31 ----
        float ev[3][4];
        float mx = -3.0e38f;
#pragma unroll
        for (int tau = 0; tau < 3; ++tau) {
#pragma unroll
            for (int r = 0; r < 4; ++r) {
                const int rp = q * 4 + r;
                const int kk = tau * 16 + rp - fr - 1;       // window index
                const float eb = (tau == 0) ? e0[r] : (tau == 1) ? e1[r] : e2[r];
                float v = eb + Rbuf[(kk & 31) * 18 + fr];
                const bool valid = (tau == 1) || ((tau == 0) ? (rp > fr) : (rp < fr));
                v = valid ? v : -3.0e38f;
                ev[tau][r] = v;
                mx = fmaxf(mx, v);
            }
        }
        mx = fmaxf(mx, __shfl_xor(mx, 16));
        mx = fmaxf(mx, __shfl_xor(mx, 32));
        float sum = 0.f;
#pragma unroll
        for (int tau = 0; tau < 3; ++tau)
#pragma unroll
            for (int r = 0; r < 4; ++r) {
                const float p = __expf(ev[tau][r] - mx);
                ev[tau][r] = p;
                sum += p;
            }
        sum += __shfl_xor(sum, 16);
        sum += __shfl_xor(sum, 32);
        const float inv = 1.f / sum;

        // ---- P -> Pf32 (Rbuf reuse; all energy reads already consumed) and
        //      Pbuf (bf16, chunk-swizzled) ----
#pragma unroll
        for (int tau = 0; tau < 3; ++tau)
#pragma unroll
            for (int r = 0; r < 4; ++r) {
                const int rp = q * 4 + r;
                const int kk = tau * 16 + rp - fr - 1;
                const bool valid = (tau == 1) || ((tau == 0) ? (rp > fr) : (rp < fr));
                if (valid) {
                    const float p = ev[tau][r] * inv;
                    Pf32[fr * 36 + kk] = p;
                    const int tl = tau * 16 + rp;            // t-local in [0,48)
                    Pbuf[fr * 72 + (((tl >> 3) ^ f7) << 3) + (tl & 7)] = (bf16)p;
                }
            }

        // ---- coalesced attn writeback from Pf32 ----
        asm volatile("" ::: "memory");
        {
            float* arow = &attn[((size_t)(sg0 + sl) * 8 + g) * 31];
#pragma unroll
            for (int i = 0; i < 8; ++i) {
                const int k = jj + 4 * i;
                if (k < 31) arow[k] = Pf32[sl * 36 + k];
            }
        }

        // ---- PV swapped: C[d][s] = V[d][t].P[s][t] -> bf16x4 O stores ----
        asm volatile("" ::: "memory");
        const bf16x8 a0 = *(const bf16x8*)&Pbuf[fr * 72 + ((q ^ f7) << 3)];
        const bf16x8 a1 = *(const bf16x8*)&Pbuf[fr * 72 + (((4 + q) ^ f7) << 3)];
#pragma unroll
        for (int dl = 0; dl < 2; ++dl) {
            const size_t vrow = (size_t)(b * 256 + g * 32 + dl * 16 + fr) * 4160
                              + s0 + q * 8;
            const bf16x8 v0 = *(const bf16x8*)&Vt[vrow];
            const bf16x8 v1 = *(const bf16x8*)&Vt[vrow + 32];
            f32x4 o = (f32x4){0.f, 0.f, 0.f, 0.f};
            o = MFMA16(v0, a0, o);
            o = MFMA16(v1, a1, o);
            bf16x4 pk;
#pragma unroll
            for (int r = 0; r < 4; ++r) pk[r] = (bf16)o[r];
            *(bf16x4*)&Obf[(size_t)(sg0 + fr) * 256 + g * 32 + dl * 16 + (q << 2)] = pk;
        }
    }
}

// ---------------- Kernel 3: frame = sigmoid(O @ WlT + b), MFMA -------------
__global__ __launch_bounds__(256) void frame_mfma(
    const bf16* __restrict__ O,
    const bf16* __restrict__ wlh, const bf16* __restrict__ wll,
    const float* __restrict__ bl, float* __restrict__ frame)
{
    __shared__ bf16 lds[3 * 4096];     // Ah | Bh | Bl

    const int t  = threadIdx.x;
    const int m0 = blockIdx.x * 128;

    const bf16* a_g = O + (size_t)m0 * 256;

    const int lane = t & 63, wid = t >> 6;
    const int wr = (wid >> 1) * 64, wc = (wid & 1) * 64;
    const int fr = lane & 15, cl = lane >> 4;

    f32x4 acc[4][4];
#pragma unroll
    for (int m = 0; m < 4; ++m)
#pragma unroll
        for (int n = 0; n < 4; ++n)
            acc[m][n] = (f32x4){0.f, 0.f, 0.f, 0.f};

    for (int ks = 0; ks < 8; ++ks) {
        const int ko = ks * 32;
        stage_tile(a_g + ko, lds, t);
        stage_tile(wlh + ko, lds + 4096, t);
        stage_tile(wll + ko, lds + 8192, t);
        __syncthreads();

        bf16x8 ah[4], bh[4], bl4[4];
#pragma unroll
        for (int m = 0; m < 4; ++m) ah[m] = frag_ld(lds, wr + m * 16 + fr, cl);
#pragma unroll
        for (int n = 0; n < 4; ++n) {
            bh[n]  = frag_ld(lds + 4096, wc + n * 16 + fr, cl);
            bl4[n] = frag_ld(lds + 8192, wc + n * 16 + fr, cl);
        }
#pragma unroll
        for (int m = 0; m < 4; ++m)
#pragma unroll
            for (int n = 0; n < 4; ++n) {
                acc[m][n] = MFMA16(ah[m], bh[n],  acc[m][n]);
                acc[m][n] = MFMA16(ah[m], bl4[n], acc[m][n]);
            }
        __syncthreads();
    }

#pragma unroll
    for (int m = 0; m < 4; ++m) {
        const int gr = m0 + wr + m * 16 + cl * 4;
#pragma unroll
        for (int n = 0; n < 4; ++n) {
            const int gc = wc + n * 16 + fr;
            if (gc < FOUT) {
                const float bb = bl[gc];
#pragma unroll
                for (int i = 0; i < 4; ++i) {
                    const float x = acc[m][n][i] + bb;
                    frame[(size_t)(gr + i) * FOUT + gc] = 1.f / (1.f + __expf(-x));
                }
            }
        }
    }
}

extern "C" void kernel_launch(void* const* d_in, const int* in_sizes, int n_in,
                              void* d_out, int out_size, void* d_ws, size_t ws_size,
                              hipStream_t stream) {
    (void)in_sizes; (void)n_in; (void)out_size; (void)ws_size;
    const float* spec = (const float*)d_in[0];
    const float* Wq   = (const float*)d_in[1];
    const float* Wk   = (const float*)d_in[2];
    const float* Wv   = (const float*)d_in[3];
    const float* rel  = (const float*)d_in[4];
    const float* Wl   = (const float*)d_in[5];
    const float* bl   = (const float*)d_in[6];

    float* frame = (float*)d_out;                              // [B,S,88]
    float* attn  = frame + (size_t)B_ * S_ * FOUT;             // [B,S,G,K]

    // d_out scratch (dead before the region's writer runs):
    //  sh/sl [0, 33.55M)   spec splits, dead after qkv
    //  bth/btl @33.55M     weight splits, dead after qkv
    //  relH/relL [0, 32K)  written AFTER qkv (sh dead), read by attn,
    //                      overwritten last by frame_mfma
    bf16* sh   = (bf16*)d_out;
    bf16* sl   = sh + (size_t)B_ * S_ * FIN;
    bf16* bth  = (bf16*)((char*)d_out + 33554432);
    bf16* btl  = bth + 3 * 65536;
    bf16* relH = (bf16*)d_out;
    bf16* relL = relH + 8192;

    // d_ws: Qh | Ql | Kh | Kl | Vt | WlT  (O bf16 aliases Qh, row-exact)
    bf16* Qh  = (bf16*)d_ws;
    bf16* Ql  = Qh + (size_t)8388608;
    bf16* Kh  = Ql + (size_t)8388608;
    bf16* Kl  = Kh + (size_t)8388608;
    bf16* Vt  = Kl + (size_t)8388608;          // [8][256][4160] bf16
    bf16* wlh = Vt + (size_t)8 * 256 * 4160;   // [128][256]
    bf16* wll = wlh + 128 * 256;

    vt_pad    <<<dim3(128),     256, 0, stream>>>(Vt);
    split_spec<<<dim3(4096),    256, 0, stream>>>(spec, sh, sl);
    split_w   <<<dim3(256, 3),  256, 0, stream>>>(Wq, Wk, Wv, bth, btl);
    split_wl  <<<dim3(256),     128, 0, stream>>>(Wl, wlh, wll);
    qkv_mfma  <<<dim3(1536),    256, 0, stream>>>(sh, sl, bth, btl, Qh, Ql, Kh, Kl, Vt);
    rel_prep  <<<dim3(32),      256, 0, stream>>>(rel, relH, relL);
    attn_mfma <<<dim3(2048),    256, 0, stream>>>(Qh, Ql, Kh, Kl, Vt, relH, relL, attn, Qh);
    frame_mfma<<<dim3(256),     256, 0, stream>>>(Qh, wlh, wll, bl, frame);
}

// Round 8
// 116.747 us; speedup vs baseline: 4.2413x; 1.1010x over previous
//
#include <hip/hip_runtime.h>
#include <hip/hip_bf16.h>
#include <math.h>

#define B_   8
#define S_   4096
#define FIN  256
#define C_   256
#define G_   8
#define D_   32
#define K_   31
#define PAD_ 15
#define FOUT 88

typedef __bf16 bf16;
typedef __attribute__((ext_vector_type(8))) __bf16 bf16x8;
typedef __attribute__((ext_vector_type(4))) __bf16 bf16x4;
typedef __attribute__((ext_vector_type(4))) float f32x4;

#define MFMA16(A, B, C) __builtin_amdgcn_mfma_f32_16x16x32_bf16(A, B, C, 0, 0, 0)

// ---------------- Kernel P: all preps merged (one launch) ------------------
// blocks [0,768): split+transpose Wq/Wk/Wv -> bth/btl [w][n][k]
// blocks [768,896): split+transpose Wl -> wlh/wll [128 n][256 k] (n>=88 zero)
// blocks [896,1024): zero Vt pad zones
// blocks [1024,1056): rel -> plain bf16 hi/lo planes [8 g][32 k][32 d]
__global__ __launch_bounds__(256) void prep_all(
    const float* __restrict__ Wq, const float* __restrict__ Wk,
    const float* __restrict__ Wv, const float* __restrict__ Wl,
    const float* __restrict__ rel,
    bf16* __restrict__ bth, bf16* __restrict__ btl,
    bf16* __restrict__ wlh, bf16* __restrict__ wll,
    bf16* __restrict__ Vt,
    bf16* __restrict__ relH, bf16* __restrict__ relL)
{
    const int bid = blockIdx.x;
    const int t   = threadIdx.x;

    if (bid < 768) {                       // ---- split_w ----
        const int w = bid >> 8;            // 0..2
        const int k = bid & 255;
        const float* W = (w == 0) ? Wq : (w == 1) ? Wk : Wv;
        const float x = W[(size_t)k * 256 + t];
        const bf16 h = (bf16)x;
        const size_t o = (size_t)w * 65536 + (size_t)t * 256 + k;
        bth[o] = h;
        btl[o] = (bf16)(x - (float)h);
    } else if (bid < 896) {                // ---- split_wl ----
        const int k = (bid - 768) * 2 + (t >> 7);
        const int n = t & 127;
        const float x = (n < FOUT) ? Wl[(size_t)k * FOUT + n] : 0.f;
        const bf16 h = (bf16)x;
        wlh[(size_t)n * 256 + k] = h;
        wll[(size_t)n * 256 + k] = (bf16)(x - (float)h);
    } else if (bid < 1024) {               // ---- vt_pad ----
        const int idx = (bid - 896) * 256 + t;      // 32768
        const int bd  = idx >> 4;
        const int pos = (idx & 15) * 4;
        const int off = (pos < 16) ? pos : 4096 + pos;
        bf16x4 z = {};
        *(bf16x4*)&Vt[(size_t)bd * 4160 + off] = z;
    } else {                               // ---- rel_prep ----
        const int idx = (bid - 1024) * 256 + t;     // 8192
        const int g = idx >> 10, k = (idx >> 5) & 31, d = idx & 31;
        const float v = (k < 31) ? rel[(size_t)(g * 32 + d) * 31 + k] : 0.f;
        const bf16 h = (bf16)v;
        relH[idx] = h;
        relL[idx] = (bf16)(v - (float)h);
    }
}

// ---------------- shared helpers: staged swizzled tiles --------------------
__device__ __forceinline__ void gload16(const bf16* g, bf16* l) {
    __builtin_amdgcn_global_load_lds(
        (const __attribute__((address_space(1))) void*)g,
        (__attribute__((address_space(3))) void*)l, 16, 0, 0);
}

__device__ __forceinline__ void gload16f(const float* g, float* l) {
    __builtin_amdgcn_global_load_lds(
        (const __attribute__((address_space(1))) void*)g,
        (__attribute__((address_space(3))) void*)l, 16, 0, 0);
}

// bf16 [128 r][32 k] tile, 16B-chunk swizzle: stored = logical ^ ((r>>1)&3)
__device__ __forceinline__ void stage_tile(const bf16* g, bf16* l, int t) {
    const int lg = ((t & 3) ^ ((t >> 3) & 3)) * 8;
    const int r0 = t >> 2;
    const int r1 = 64 + (t >> 2);
    const int u0 = (t & ~63) * 8;
    gload16(g + (size_t)r0 * 256 + lg, l + u0);
    gload16(g + (size_t)r1 * 256 + lg, l + u0 + 2048);
}

__device__ __forceinline__ bf16x8 frag_ld(const bf16* l, int r, int cl) {
    return *(const bf16x8*)&l[r * 32 + ((cl ^ ((r >> 1) & 3)) << 3)];
}

// f32 [128 r][32 k] tile (16 KB), 8 chunks/row, swizzle: stored = logical ^ (r&7)
__device__ __forceinline__ void stage_tileA(const float* g, float* l, int t) {
#pragma unroll
    for (int i = 0; i < 4; ++i) {
        const int li  = i * 256 + t;           // stored chunk index 0..1023
        const int row = li >> 3;
        const int sc  = li & 7;
        const int src = row * 256 + ((sc ^ (row & 7)) << 2);
        gload16f(g + src, l + ((i << 8) + (t & ~63)) * 4);   // uniform base
    }
}

// read 8 k-floats of row r, k-group cl, convert to bf16 hi/lo frags in-reg
__device__ __forceinline__ void frag_ldA(const float* A, int r, int cl,
                                         bf16x8* hi, bf16x8* lo) {
    const int base = r * 32;
    const f32x4 a0 = *(const f32x4*)&A[base + ((( 2 * cl)     ^ (r & 7)) << 2)];
    const f32x4 a1 = *(const f32x4*)&A[base + (((2 * cl + 1)  ^ (r & 7)) << 2)];
    bf16x8 h, l;
#pragma unroll
    for (int j = 0; j < 4; ++j) {
        const bf16 h0 = (bf16)a0[j]; h[j]     = h0; l[j]     = (bf16)(a0[j] - (float)h0);
        const bf16 h1 = (bf16)a1[j]; h[4 + j] = h1; l[4 + j] = (bf16)(a1[j] - (float)h1);
    }
    *hi = h; *lo = l;
}

__device__ __forceinline__ bf16x8 frag_ldA_hi(const float* A, int r, int cl) {
    const int base = r * 32;
    const f32x4 a0 = *(const f32x4*)&A[base + ((( 2 * cl)     ^ (r & 7)) << 2)];
    const f32x4 a1 = *(const f32x4*)&A[base + (((2 * cl + 1)  ^ (r & 7)) << 2)];
    bf16x8 h;
#pragma unroll
    for (int j = 0; j < 4; ++j) { h[j] = (bf16)a0[j]; h[4 + j] = (bf16)a1[j]; }
    return h;
}

// ---------------- Kernel 1: QKV projection, fused f32-A split + MFMA -------
// A = spec f32 staged directly (16 KB tile); hi/lo derived in registers.
// B = pre-split weights bf16. Q,K: 3-term; V: 2-term. Single-buffer 32 KB.
__global__ __launch_bounds__(256) void qkv_mfma(
    const float* __restrict__ spec,
    const bf16* __restrict__ bth, const bf16* __restrict__ btl,
    bf16* __restrict__ Qh, bf16* __restrict__ Ql,
    bf16* __restrict__ Kh, bf16* __restrict__ Kl,
    bf16* __restrict__ Vt)
{
    __shared__ char ldsq[32768];       // Af32 16K | Bh 8K | Bl 8K
    float* Af = (float*)ldsq;
    bf16*  Bh = (bf16*)(ldsq + 16384);
    bf16*  Bl = (bf16*)(ldsq + 24576);

    const int t   = threadIdx.x;
    const int swz = ((blockIdx.x & 7) * 192) + (blockIdx.x >> 3);   // 1536 % 8 == 0
    const int mt  = swz / 6, nt = swz % 6;
    const int wt  = nt >> 1;           // 0=Q 1=K 2=V
    const int m0  = mt * 128, n0 = (nt & 1) * 128;
    const bool three = (wt < 2);

    const float* a_g = spec + (size_t)m0 * 256;
    const bf16* bh_g = bth + (size_t)wt * 65536 + (size_t)n0 * 256;
    const bf16* bl_g = btl + (size_t)wt * 65536 + (size_t)n0 * 256;

    const int lane = t & 63, wid = t >> 6;
    const int wr = (wid >> 1) * 64, wc = (wid & 1) * 64;
    const int fr = lane & 15, cl = lane >> 4;

    f32x4 acc[4][4];
#pragma unroll
    for (int m = 0; m < 4; ++m)
#pragma unroll
        for (int n = 0; n < 4; ++n)
            acc[m][n] = (f32x4){0.f, 0.f, 0.f, 0.f};

    for (int ks = 0; ks < 8; ++ks) {
        const int ko = ks * 32;
        stage_tileA(a_g + ko, Af, t);
        stage_tile(bh_g + ko, Bh, t);
        stage_tile(bl_g + ko, Bl, t);
        __syncthreads();

        bf16x8 bh8[4], bl8[4];
#pragma unroll
        for (int n = 0; n < 4; ++n) {
            bh8[n] = frag_ld(Bh, wc + n * 16 + fr, cl);
            bl8[n] = frag_ld(Bl, wc + n * 16 + fr, cl);
        }
        if (three) {
            bf16x8 ahh[4], ahl[4];
#pragma unroll
            for (int m = 0; m < 4; ++m)
                frag_ldA(Af, wr + m * 16 + fr, cl, &ahh[m], &ahl[m]);
#pragma unroll
            for (int m = 0; m < 4; ++m)
#pragma unroll
                for (int n = 0; n < 4; ++n) {
                    acc[m][n] = MFMA16(ahh[m], bh8[n], acc[m][n]);
                    acc[m][n] = MFMA16(ahh[m], bl8[n], acc[m][n]);
                    acc[m][n] = MFMA16(ahl[m], bh8[n], acc[m][n]);
                }
        } else {
            bf16x8 ahh[4];
#pragma unroll
            for (int m = 0; m < 4; ++m)
                ahh[m] = frag_ldA_hi(Af, wr + m * 16 + fr, cl);
#pragma unroll
            for (int m = 0; m < 4; ++m)
#pragma unroll
                for (int n = 0; n < 4; ++n) {
                    acc[m][n] = MFMA16(ahh[m], bh8[n], acc[m][n]);
                    acc[m][n] = MFMA16(ahh[m], bl8[n], acc[m][n]);
                }
        }
        __syncthreads();
    }

    // C/D layout: col = lane&15, row = (lane>>4)*4 + reg
    if (wt < 2) {
        bf16* Oh = (wt == 0) ? Qh : Kh;
        bf16* Ol = (wt == 0) ? Ql : Kl;
#pragma unroll
        for (int m = 0; m < 4; ++m) {
            const int gr = m0 + wr + m * 16 + cl * 4;
#pragma unroll
            for (int n = 0; n < 4; ++n) {
                const int gc = n0 + wc + n * 16 + fr;
#pragma unroll
                for (int i = 0; i < 4; ++i) {
                    const float v = acc[m][n][i];
                    const bf16 hh = (bf16)v;
                    const size_t off = (size_t)(gr + i) * 256 + gc;
                    Oh[off] = hh;
                    Ol[off] = (bf16)(v - (float)hh);
                }
            }
        }
    } else {
#pragma unroll
        for (int m = 0; m < 4; ++m) {
            const int gr = m0 + wr + m * 16 + cl * 4;
            const int bb = gr >> 12, sr = gr & 4095;
#pragma unroll
            for (int n = 0; n < 4; ++n) {
                const int gc = n0 + wc + n * 16 + fr;
                bf16x4 pk;
#pragma unroll
                for (int i = 0; i < 4; ++i) pk[i] = (bf16)acc[m][n][i];
                *(bf16x4*)&Vt[(size_t)(bb * 256 + gc) * 4160 + 16 + sr] = pk;
            }
        }
    }
}

// ---------------- Kernel 2: MFMA windowed attention (no-barrier version) ---
__global__ __launch_bounds__(256) void attn_mfma(
    const bf16* __restrict__ Qh, const bf16* __restrict__ Ql,
    const bf16* __restrict__ Kh, const bf16* __restrict__ Kl,
    const bf16* __restrict__ Vt,
    const bf16* __restrict__ relH, const bf16* __restrict__ relL,
    float* __restrict__ attn, bf16* __restrict__ Obf)
{
    __shared__ char ldsb[18432];   // 4 waves x (Rbuf/Pf32 2304 | Pbuf 2304)

    const int t    = threadIdx.x;
    const int wid  = t >> 6;
    const int lane = t & 63;
    const int fr   = lane & 15;     // s-col / frag row
    const int q    = lane >> 4;     // k-chunk group
    const int f7   = fr & 7;
    const int sl   = lane >> 2;     // writeback row 0..15
    const int jj   = lane & 3;

    const int bid2 = ((blockIdx.x & 7) << 8) | (blockIdx.x >> 3);   // 2048 % 8 == 0
    const int sg0  = bid2 << 4;
    const int b    = sg0 >> 12;
    const int s0   = sg0 & 4095;

    float* Rbuf = (float*)(ldsb + wid * 4608);          // [32 k][18] f32
    float* Pf32 = Rbuf;                                 // reused: [16 s][36] f32
    bf16*  Pbuf = (bf16*) (ldsb + wid * 4608 + 2304);   // [16 s][72] bf16

    {   // zero Pbuf once (valid band positions rewritten every head)
        uint* p32 = (uint*)Pbuf;
#pragma unroll
        for (int j = 0; j < 9; ++j) p32[lane + 64 * j] = 0u;
    }

    const size_t rowQ = (size_t)(sg0 + fr) * 256;

#pragma unroll
    for (int h = 0; h < 2; ++h) {
        asm volatile("" ::: "memory");
        const int g   = wid * 2 + h;
        const int dof = g * 32 + q * 8;

        const bf16x8 qh8 = *(const bf16x8*)&Qh[rowQ + dof];
        const bf16x8 ql8 = *(const bf16x8*)&Ql[rowQ + dof];

        // ---- QK^T tiles: C[t][s], t0 = s0-16+16*tau ----
        f32x4 e0, e1, e2;
#pragma unroll
        for (int tau = 0; tau < 3; ++tau) {
            const int trel = s0 - 16 + tau * 16 + fr;
            bf16x8 kh8 = {}, kl8 = {};
            if ((unsigned)trel < 4096u) {
                const size_t rk = ((size_t)(b << 12) + trel) * 256 + dof;
                kh8 = *(const bf16x8*)&Kh[rk];
                kl8 = *(const bf16x8*)&Kl[rk];
            }
            f32x4 a = (f32x4){0.f, 0.f, 0.f, 0.f};
            a = MFMA16(kh8, qh8, a);
            a = MFMA16(kh8, ql8, a);
            a = MFMA16(kl8, qh8, a);
            if (tau == 0) e0 = a; else if (tau == 1) e1 = a; else e2 = a;
        }

        // ---- R[k][s] = rel_g^T . Q_g ; A-frags straight from global ----
#pragma unroll
        for (int kap = 0; kap < 2; ++kap) {
            const size_t ro = (size_t)(g * 32 + kap * 16 + fr) * 32 + q * 8;
            const bf16x8 rh8 = *(const bf16x8*)&relH[ro];
            const bf16x8 rl8 = *(const bf16x8*)&relL[ro];
            f32x4 rc = (f32x4){0.f, 0.f, 0.f, 0.f};
            rc = MFMA16(rh8, qh8, rc);
            rc = MFMA16(rh8, ql8, rc);
            rc = MFMA16(rl8, qh8, rc);
#pragma unroll
            for (int r = 0; r < 4; ++r)
                Rbuf[(kap * 16 + q * 4 + r) * 18 + fr] = rc[r];
        }

        // ---- energies: e + R[t-s+15], band mask, softmax over 31 ----
        float ev[3][4];
        float mx = -3.0e38f;
#pragma unroll
        for (int tau = 0; tau < 3; ++tau) {
#pragma unroll
            for (int r = 0; r < 4; ++r) {
                const int rp = q * 4 + r;
                const int kk = tau * 16 + rp - fr - 1;       // window index
                const float eb = (tau == 0) ? e0[r] : (tau == 1) ? e1[r] : e2[r];
                float v = eb + Rbuf[(kk & 31) * 18 + fr];
                const bool valid = (tau == 1) || ((tau == 0) ? (rp > fr) : (rp < fr));
                v = valid ? v : -3.0e38f;
                ev[tau][r] = v;
                mx = fmaxf(mx, v);
            }
        }
        mx = fmaxf(mx, __shfl_xor(mx, 16));
        mx = fmaxf(mx, __shfl_xor(mx, 32));
        float sum = 0.f;
#pragma unroll
        for (int tau = 0; tau < 3; ++tau)
#pragma unroll
            for (int r = 0; r < 4; ++r) {
                const float p = __expf(ev[tau][r] - mx);
                ev[tau][r] = p;
                sum += p;
            }
        sum += __shfl_xor(sum, 16);
        sum += __shfl_xor(sum, 32);
        const float inv = 1.f / sum;

        // ---- P -> Pf32 (Rbuf reuse) and Pbuf (bf16, chunk-swizzled) ----
#pragma unroll
        for (int tau = 0; tau < 3; ++tau)
#pragma unroll
            for (int r = 0; r < 4; ++r) {
                const int rp = q * 4 + r;
                const int kk = tau * 16 + rp - fr - 1;
                const bool valid = (tau == 1) || ((tau == 0) ? (rp > fr) : (rp < fr));
                if (valid) {
                    const float p = ev[tau][r] * inv;
                    Pf32[fr * 36 + kk] = p;
                    const int tl = tau * 16 + rp;            // t-local in [0,48)
                    Pbuf[fr * 72 + (((tl >> 3) ^ f7) << 3) + (tl & 7)] = (bf16)p;
                }
            }

        // ---- coalesced attn writeback from Pf32 ----
        asm volatile("" ::: "memory");
        {
            float* arow = &attn[((size_t)(sg0 + sl) * 8 + g) * 31];
#pragma unroll
            for (int i = 0; i < 8; ++i) {
                const int k = jj + 4 * i;
                if (k < 31) arow[k] = Pf32[sl * 36 + k];
            }
        }

        // ---- PV swapped: C[d][s] = V[d][t].P[s][t] -> bf16x4 O stores ----
        asm volatile("" ::: "memory");
        const bf16x8 a0 = *(const bf16x8*)&Pbuf[fr * 72 + ((q ^ f7) << 3)];
        const bf16x8 a1 = *(const bf16x8*)&Pbuf[fr * 72 + (((4 + q) ^ f7) << 3)];
#pragma unroll
        for (int dl = 0; dl < 2; ++dl) {
            const size_t vrow = (size_t)(b * 256 + g * 32 + dl * 16 + fr) * 4160
                              + s0 + q * 8;
            const bf16x8 v0 = *(const bf16x8*)&Vt[vrow];
            const bf16x8 v1 = *(const bf16x8*)&Vt[vrow + 32];
            f32x4 o = (f32x4){0.f, 0.f, 0.f, 0.f};
            o = MFMA16(v0, a0, o);
            o = MFMA16(v1, a1, o);
            bf16x4 pk;
#pragma unroll
            for (int r = 0; r < 4; ++r) pk[r] = (bf16)o[r];
            *(bf16x4*)&Obf[(size_t)(sg0 + fr) * 256 + g * 32 + dl * 16 + (q << 2)] = pk;
        }
    }
}

// ---------------- Kernel 3: frame = sigmoid(O @ WlT + b), MFMA -------------
__global__ __launch_bounds__(256) void frame_mfma(
    const bf16* __restrict__ O,
    const bf16* __restrict__ wlh, const bf16* __restrict__ wll,
    const float* __restrict__ bl, float* __restrict__ frame)
{
    __shared__ bf16 lds[3 * 4096];     // Ah | Bh | Bl

    const int t  = threadIdx.x;
    const int m0 = blockIdx.x * 128;

    const bf16* a_g = O + (size_t)m0 * 256;

    const int lane = t & 63, wid = t >> 6;
    const int wr = (wid >> 1) * 64, wc = (wid & 1) * 64;
    const int fr = lane & 15, cl = lane >> 4;

    f32x4 acc[4][4];
#pragma unroll
    for (int m = 0; m < 4; ++m)
#pragma unroll
        for (int n = 0; n < 4; ++n)
            acc[m][n] = (f32x4){0.f, 0.f, 0.f, 0.f};

    for (int ks = 0; ks < 8; ++ks) {
        const int ko = ks * 32;
        stage_tile(a_g + ko, lds, t);
        stage_tile(wlh + ko, lds + 4096, t);
        stage_tile(wll + ko, lds + 8192, t);
        __syncthreads();

        bf16x8 ah[4], bh[4], bl4[4];
#pragma unroll
        for (int m = 0; m < 4; ++m) ah[m] = frag_ld(lds, wr + m * 16 + fr, cl);
#pragma unroll
        for (int n = 0; n < 4; ++n) {
            bh[n]  = frag_ld(lds + 4096, wc + n * 16 + fr, cl);
            bl4[n] = frag_ld(lds + 8192, wc + n * 16 + fr, cl);
        }
#pragma unroll
        for (int m = 0; m < 4; ++m)
#pragma unroll
            for (int n = 0; n < 4; ++n) {
                acc[m][n] = MFMA16(ah[m], bh[n],  acc[m][n]);
                acc[m][n] = MFMA16(ah[m], bl4[n], acc[m][n]);
            }
        __syncthreads();
    }

#pragma unroll
    for (int m = 0; m < 4; ++m) {
        const int gr = m0 + wr + m * 16 + cl * 4;
#pragma unroll
        for (int n = 0; n < 4; ++n) {
            const int gc = wc + n * 16 + fr;
            if (gc < FOUT) {
                const float bb = bl[gc];
#pragma unroll
                for (int i = 0; i < 4; ++i) {
                    const float x = acc[m][n][i] + bb;
                    frame[(size_t)(gr + i) * FOUT + gc] = 1.f / (1.f + __expf(-x));
                }
            }
        }
    }
}

extern "C" void kernel_launch(void* const* d_in, const int* in_sizes, int n_in,
                              void* d_out, int out_size, void* d_ws, size_t ws_size,
                              hipStream_t stream) {
    (void)in_sizes; (void)n_in; (void)out_size; (void)ws_size;
    const float* spec = (const float*)d_in[0];
    const float* Wq   = (const float*)d_in[1];
    const float* Wk   = (const float*)d_in[2];
    const float* Wv   = (const float*)d_in[3];
    const float* rel  = (const float*)d_in[4];
    const float* Wl   = (const float*)d_in[5];
    const float* bl   = (const float*)d_in[6];

    float* frame = (float*)d_out;                              // [B,S,88]
    float* attn  = frame + (size_t)B_ * S_ * FOUT;             // [B,S,G,K]

    // d_out scratch (dead before the region's writer runs):
    //  relH/relL [0, 32K)  ⊂ frame region: prep writes, attn reads, frame overwrites last
    //  bth/btl @33.55M     ⊂ attn region: prep writes, qkv reads, attn overwrites
    bf16* bth  = (bf16*)((char*)d_out + 33554432);
    bf16* btl  = bth + 3 * 65536;
    bf16* relH = (bf16*)d_out;
    bf16* relL = relH + 8192;

    // d_ws: Qh | Ql | Kh | Kl | Vt | WlT  (O bf16 aliases Qh, row-exact)
    bf16* Qh  = (bf16*)d_ws;
    bf16* Ql  = Qh + (size_t)8388608;
    bf16* Kh  = Ql + (size_t)8388608;
    bf16* Kl  = Kh + (size_t)8388608;
    bf16* Vt  = Kl + (size_t)8388608;          // [8][256][4160] bf16
    bf16* wlh = Vt + (size_t)8 * 256 * 4160;   // [128][256]
    bf16* wll = wlh + 128 * 256;

    prep_all  <<<dim3(1056), 256, 0, stream>>>(Wq, Wk, Wv, Wl, rel,
                                               bth, btl, wlh, wll, Vt, relH, relL);
    qkv_mfma  <<<dim3(1536), 256, 0, stream>>>(spec, bth, btl, Qh, Ql, Kh, Kl, Vt);
    attn_mfma <<<dim3(2048), 256, 0, stream>>>(Qh, Ql, Kh, Kl, Vt, relH, relL, attn, Qh);
    frame_mfma<<<dim3(256),  256, 0, stream>>>(Qh, wlh, wll, bl, frame);
}